// Round 4
// baseline (1361.288 us; speedup 1.0000x reference)
//
#include <hip/hip_runtime.h>
#include <hip/hip_bf16.h>

// Mamba2 mixer forward, MI355X. B=2, L=2048, D_MODEL=2048, H=64, P=64, N=128,
// G=1, K=4, CHUNK=256. T = 4096 tokens, 16 chunks.
// Precision plan: split-bf16 (hi+lo) in_proj GEMM -> fp32 hbc -> fp32 conv ->
// fp32 scan (CBT in VALU fp32) -> bf16 only at gate store and out_proj GEMM.

#define BF16 __hip_bfloat16

typedef __attribute__((ext_vector_type(8))) short bf16x8;
typedef __attribute__((ext_vector_type(4))) float f32x4;

#define GLD16(gp, lp) __builtin_amdgcn_global_load_lds( \
    (__attribute__((address_space(1))) void*)(gp),      \
    (__attribute__((address_space(3))) void*)(lp), 16, 0, 0)

__device__ __forceinline__ float bf2f(BF16 x) {
  unsigned short us = *reinterpret_cast<unsigned short*>(&x);
  return __uint_as_float((unsigned)us << 16);
}
__device__ __forceinline__ float4 load4bf(const BF16* p) {
  ushort4 u = *reinterpret_cast<const ushort4*>(p);
  float4 r;
  r.x = __uint_as_float((unsigned)u.x << 16);
  r.y = __uint_as_float((unsigned)u.y << 16);
  r.z = __uint_as_float((unsigned)u.z << 16);
  r.w = __uint_as_float((unsigned)u.w << 16);
  return r;
}
__device__ __forceinline__ unsigned short f2bfu(float v) {
  BF16 b = __float2bfloat16(v);
  return *reinterpret_cast<unsigned short*>(&b);
}
__device__ __forceinline__ float siluf(float x) { return x / (1.f + expf(-x)); }

// ------------------------------------------------ cast X -> bf16 hi + lo
__global__ __launch_bounds__(256) void cast_split(const float* __restrict__ s,
                                                  BF16* __restrict__ dhi,
                                                  BF16* __restrict__ dlo) {
  long i = ((long)blockIdx.x * 256 + threadIdx.x) * 4;
  float4 v = *reinterpret_cast<const float4*>(s + i);
  ushort4 uh, ul;
  float w;
  uh.x = f2bfu(v.x); w = __uint_as_float((unsigned)uh.x << 16); ul.x = f2bfu(v.x - w);
  uh.y = f2bfu(v.y); w = __uint_as_float((unsigned)uh.y << 16); ul.y = f2bfu(v.y - w);
  uh.z = f2bfu(v.z); w = __uint_as_float((unsigned)uh.z << 16); ul.z = f2bfu(v.z - w);
  uh.w = f2bfu(v.w); w = __uint_as_float((unsigned)uh.w << 16); ul.w = f2bfu(v.w - w);
  *reinterpret_cast<ushort4*>(dhi + i) = uh;
  *reinterpret_cast<ushort4*>(dlo + i) = ul;
}

// --------------------------- transpose Win cols [0,8448) -> hi/lo, [n][k] bf16
__global__ __launch_bounds__(256) void transpose_split(const float* __restrict__ src,
                                                       BF16* __restrict__ dhi,
                                                       BF16* __restrict__ dlo) {
  __shared__ float tile[32][33];
  int c0 = blockIdx.x * 32, r0 = blockIdx.y * 32;  // c: [0,8448), r: [0,2048)
  int tx = threadIdx.x, ty = threadIdx.y;          // 32 x 8
#pragma unroll
  for (int i = 0; i < 4; i++)
    tile[ty + i * 8][tx] = src[(long)(r0 + ty + i * 8) * 8512 + c0 + tx];
  __syncthreads();
#pragma unroll
  for (int i = 0; i < 4; i++) {
    int c = c0 + ty + i * 8, r = r0 + tx;
    float v = tile[tx][ty + i * 8];
    unsigned short h = f2bfu(v);
    float w = __uint_as_float((unsigned)h << 16);
    unsigned short l = f2bfu(v - w);
    *reinterpret_cast<unsigned short*>(dhi + (long)c * 2048 + r) = h;
    *reinterpret_cast<unsigned short*>(dlo + (long)c * 2048 + r) = l;
  }
}

// ------------------ transpose+cast fp32 RxC -> bf16 [C][R] (for out_proj W)
__global__ __launch_bounds__(256) void transpose_cast(const float* __restrict__ src,
                                                      BF16* __restrict__ dst,
                                                      int R, int C) {
  __shared__ float tile[32][33];
  int c0 = blockIdx.x * 32, r0 = blockIdx.y * 32;
  int tx = threadIdx.x, ty = threadIdx.y;
#pragma unroll
  for (int i = 0; i < 4; i++)
    tile[ty + i * 8][tx] = src[(long)(r0 + ty + i * 8) * C + c0 + tx];
  __syncthreads();
#pragma unroll
  for (int i = 0; i < 4; i++) {
    int c = c0 + ty + i * 8, r = r0 + tx;
    dst[(long)c * R + r] = __float2bfloat16(tile[tx][ty + i * 8]);
  }
}

// ---------------------------------- split-bf16 in_proj GEMM (fp32-accurate)
// acc = Ahi*Whi + Ahi*Wlo + Alo*Whi over K=2048. M=4096, N=8448.
// cols <4096 -> gate (bf16), cols >=4096 -> hbcf (fp32, ldc 4352).
__global__ __launch_bounds__(256) void gemm_split(const BF16* __restrict__ Ahi,
                                                  const BF16* __restrict__ Alo,
                                                  const BF16* __restrict__ Whi,
                                                  const BF16* __restrict__ Wlo,
                                                  BF16* __restrict__ gate,
                                                  float* __restrict__ hbcf) {
  __shared__ uint4 AsH4[512], AsL4[512], BsH4[512], BsL4[512];  // 32 KB
  BF16* AsH = (BF16*)AsH4; BF16* AsL = (BF16*)AsL4;
  BF16* BsH = (BF16*)BsH4; BF16* BsL = (BF16*)BsL4;
  const int tid = threadIdx.x;
  const int wv = tid >> 6;
  const int lane = tid & 63;
  const long abase = (long)blockIdx.y * 128 * 2048;
  const long bbase = (long)blockIdx.x * 128 * 2048;
  const int c0 = wv * 128 + lane;
  const int c1 = c0 + 64;
  const long ra0 = (long)(c0 >> 2) * 2048 + (c0 & 3) * 8;
  const long ra1 = (long)(c1 >> 2) * 2048 + (c1 & 3) * 8;
  f32x4 acc[4][4];
#pragma unroll
  for (int mi = 0; mi < 4; mi++)
#pragma unroll
    for (int ni = 0; ni < 4; ni++) acc[mi][ni] = f32x4{0.f, 0.f, 0.f, 0.f};
  const int mrow = (wv & 1) * 64 + (lane & 15);
  const int nrow = (wv >> 1) * 64 + (lane & 15);
  const int koff = (lane >> 4) * 8;
  for (int k0 = 0; k0 < 2048; k0 += 32) {
    GLD16(Ahi + abase + ra0 + k0, (char*)AsH + c0 * 16);
    GLD16(Ahi + abase + ra1 + k0, (char*)AsH + c1 * 16);
    GLD16(Alo + abase + ra0 + k0, (char*)AsL + c0 * 16);
    GLD16(Alo + abase + ra1 + k0, (char*)AsL + c1 * 16);
    GLD16(Whi + bbase + ra0 + k0, (char*)BsH + c0 * 16);
    GLD16(Whi + bbase + ra1 + k0, (char*)BsH + c1 * 16);
    GLD16(Wlo + bbase + ra0 + k0, (char*)BsL + c0 * 16);
    GLD16(Wlo + bbase + ra1 + k0, (char*)BsL + c1 * 16);
    __syncthreads();
    bf16x8 ah[4], al[4], bh[4], bl[4];
#pragma unroll
    for (int mi = 0; mi < 4; mi++) {
      ah[mi] = *(const bf16x8*)(AsH + (mrow + mi * 16) * 32 + koff);
      al[mi] = *(const bf16x8*)(AsL + (mrow + mi * 16) * 32 + koff);
    }
#pragma unroll
    for (int ni = 0; ni < 4; ni++) {
      bh[ni] = *(const bf16x8*)(BsH + (nrow + ni * 16) * 32 + koff);
      bl[ni] = *(const bf16x8*)(BsL + (nrow + ni * 16) * 32 + koff);
    }
#pragma unroll
    for (int mi = 0; mi < 4; mi++)
#pragma unroll
      for (int ni = 0; ni < 4; ni++) {
        acc[mi][ni] = __builtin_amdgcn_mfma_f32_16x16x32_bf16(ah[mi], bh[ni], acc[mi][ni], 0, 0, 0);
        acc[mi][ni] = __builtin_amdgcn_mfma_f32_16x16x32_bf16(ah[mi], bl[ni], acc[mi][ni], 0, 0, 0);
        acc[mi][ni] = __builtin_amdgcn_mfma_f32_16x16x32_bf16(al[mi], bh[ni], acc[mi][ni], 0, 0, 0);
      }
    __syncthreads();
  }
  const int m0 = blockIdx.y * 128 + (wv & 1) * 64;
  const int n0 = blockIdx.x * 128 + (wv >> 1) * 64;
  const int cl = lane & 15, rq = (lane >> 4) * 4;
  if (n0 < 4096) {
#pragma unroll
    for (int mi = 0; mi < 4; mi++)
#pragma unroll
      for (int r = 0; r < 4; r++) {
        long rowoff = (long)(m0 + mi * 16 + rq + r) * 4096 + n0 + cl;
#pragma unroll
        for (int ni = 0; ni < 4; ni++)
          gate[rowoff + ni * 16] = __float2bfloat16(acc[mi][ni][r]);
      }
  } else {
#pragma unroll
    for (int mi = 0; mi < 4; mi++)
#pragma unroll
      for (int r = 0; r < 4; r++) {
        long rowoff = (long)(m0 + mi * 16 + rq + r) * 4352 + (n0 - 4096) + cl;
#pragma unroll
        for (int ni = 0; ni < 4; ni++) hbcf[rowoff + ni * 16] = acc[mi][ni][r];
      }
  }
}

// ------------------------------------------------------------- bf16 GEMM (B^T)
// out[M,N] fp32 = A[M,K] * Bt[N,K]^T.  (used for out_proj)
__global__ __launch_bounds__(256) void gemm_bt(const BF16* __restrict__ A,
                                               const BF16* __restrict__ Bt,
                                               float* __restrict__ Cf,
                                               int K, int ldc) {
  __shared__ uint4 As4[512];
  __shared__ uint4 Bs4[512];
  BF16* As = (BF16*)As4;
  BF16* Bs = (BF16*)Bs4;
  const int tid = threadIdx.x;
  const int wv = tid >> 6;
  const int lane = tid & 63;
  const BF16* Ab = A + (long)blockIdx.y * 128 * K;
  const BF16* Bb = Bt + (long)blockIdx.x * 128 * K;
  const int c0 = wv * 128 + lane;
  const int c1 = c0 + 64;
  const long ra0 = (long)(c0 >> 2) * K + (c0 & 3) * 8;
  const long ra1 = (long)(c1 >> 2) * K + (c1 & 3) * 8;
  f32x4 acc[4][4];
#pragma unroll
  for (int mi = 0; mi < 4; mi++)
#pragma unroll
    for (int ni = 0; ni < 4; ni++) acc[mi][ni] = f32x4{0.f, 0.f, 0.f, 0.f};
  const int mrow = (wv & 1) * 64 + (lane & 15);
  const int nrow = (wv >> 1) * 64 + (lane & 15);
  const int koff = (lane >> 4) * 8;
  for (int k0 = 0; k0 < K; k0 += 32) {
    GLD16(Ab + ra0 + k0, (char*)As + c0 * 16);
    GLD16(Ab + ra1 + k0, (char*)As + c1 * 16);
    GLD16(Bb + ra0 + k0, (char*)Bs + c0 * 16);
    GLD16(Bb + ra1 + k0, (char*)Bs + c1 * 16);
    __syncthreads();
    bf16x8 af[4], bfr[4];
#pragma unroll
    for (int mi = 0; mi < 4; mi++)
      af[mi] = *(const bf16x8*)(As + (mrow + mi * 16) * 32 + koff);
#pragma unroll
    for (int ni = 0; ni < 4; ni++)
      bfr[ni] = *(const bf16x8*)(Bs + (nrow + ni * 16) * 32 + koff);
#pragma unroll
    for (int mi = 0; mi < 4; mi++)
#pragma unroll
      for (int ni = 0; ni < 4; ni++)
        acc[mi][ni] = __builtin_amdgcn_mfma_f32_16x16x32_bf16(af[mi], bfr[ni],
                                                              acc[mi][ni], 0, 0, 0);
    __syncthreads();
  }
  const int m0 = blockIdx.y * 128 + (wv & 1) * 64;
  const int n0 = blockIdx.x * 128 + (wv >> 1) * 64;
  const int cl = lane & 15, rq = (lane >> 4) * 4;
#pragma unroll
  for (int mi = 0; mi < 4; mi++)
#pragma unroll
    for (int r = 0; r < 4; r++) {
      long rowoff = (long)(m0 + mi * 16 + rq + r) * ldc + n0 + cl;
#pragma unroll
      for (int ni = 0; ni < 4; ni++) Cf[rowoff + ni * 16] = acc[mi][ni][r];
    }
}

// ---------------------------------------- fp32 dt pre-activation (exact slice)
__global__ __launch_bounds__(256) void dtz_kernel(const float* __restrict__ hs,
                                                  const float* __restrict__ Win,
                                                  float* __restrict__ zf) {
  __shared__ float Xs[4][2048];
  int t0 = blockIdx.x * 4;
  int tid = threadIdx.x;
#pragma unroll
  for (int i = 0; i < 8; i++) {
    int e = tid * 4 + i * 1024;
    int tok = e >> 11, k = e & 2047;
    *reinterpret_cast<float4*>(&Xs[tok][k]) =
        *reinterpret_cast<const float4*>(&hs[(long)(t0 + tok) * 2048 + k]);
  }
  __syncthreads();
  int h = tid & 63, tg = tid >> 6;
  float a0 = 0.f, a1 = 0.f, a2 = 0.f, a3 = 0.f;
  const float* wcol = Win + 8448 + h;
  for (int k = 0; k < 2048; k += 4) {
    a0 = fmaf(Xs[tg][k + 0], wcol[(long)(k + 0) * 8512], a0);
    a1 = fmaf(Xs[tg][k + 1], wcol[(long)(k + 1) * 8512], a1);
    a2 = fmaf(Xs[tg][k + 2], wcol[(long)(k + 2) * 8512], a2);
    a3 = fmaf(Xs[tg][k + 3], wcol[(long)(k + 3) * 8512], a3);
  }
  zf[(long)(t0 + tg) * 64 + h] = (a0 + a1) + (a2 + a3);
}

// ------------------------------------------------------ conv(K=4)+SiLU (fp32)
__global__ __launch_bounds__(256) void conv_silu_kernel(const float* __restrict__ hbcf,
                                                        const float* __restrict__ convw,
                                                        const float* __restrict__ convb,
                                                        float* __restrict__ xf,
                                                        float* __restrict__ Bf,
                                                        float* __restrict__ Cf) {
  int q = blockIdx.x * 256 + threadIdx.x;  // [0,4352)
  int t = blockIdx.y;                      // [0,4096)
  int l = t & 2047;
  const float* col = hbcf + (long)t * 4352 + q;
  float4 wq = *reinterpret_cast<const float4*>(convw + q * 4);
  float a = convb[q];
  if (l >= 3) a += col[-3 * 4352] * wq.x;
  if (l >= 2) a += col[-2 * 4352] * wq.y;
  if (l >= 1) a += col[-1 * 4352] * wq.z;
  a += col[0] * wq.w;
  float o = siluf(a);
  if (q < 4096) xf[(long)t * 4096 + q] = o;
  else if (q < 4224) Bf[(long)t * 128 + (q - 4096)] = o;
  else Cf[(long)t * 128 + (q - 4224)] = o;
}

// ------------------------------------------------- dt softplus + chunk cumsum
__global__ __launch_bounds__(256) void dt_cum_kernel(const float* __restrict__ zf,
                                                     const float* __restrict__ dtb,
                                                     const float* __restrict__ Alog,
                                                     float* __restrict__ dt_f,
                                                     float* __restrict__ cum_f,
                                                     float* __restrict__ cuml) {
  int bc = blockIdx.x;
  int h = threadIdx.x & 63, seg = threadIdx.x >> 6;
  int t0 = bc * 256;
  float Ah = -expf(Alog[h]);
  float bias = dtb[h];
  __shared__ float segsum[4][64];
  float s = 0.f;
  for (int j = 0; j < 64; j++) {
    int t = t0 + seg * 64 + j;
    float z = zf[(long)t * 64 + h] + bias;
    float v = (z > 20.f) ? z : log1pf(expf(z));
    dt_f[(long)t * 64 + h] = v;
    s += v * Ah;
  }
  segsum[seg][h] = s;
  __syncthreads();
  float run = 0.f;
  for (int k = 0; k < seg; k++) run += segsum[k][h];
  for (int j = 0; j < 64; j++) {
    int t = t0 + seg * 64 + j;
    run += dt_f[(long)t * 64 + h] * Ah;
    cum_f[(long)t * 64 + h] = run;
  }
  if (seg == 3) cuml[bc * 64 + h] = run;
}

// ------------------------------------------------- C.B^T per chunk, fp32 VALU
// grid (16 igroups, 16 chunks). out CBT[bc][i][j], i,j in [0,256).
__global__ __launch_bounds__(256) void cbt_kernel(const float* __restrict__ Cf,
                                                  const float* __restrict__ Bf,
                                                  float* __restrict__ CBT) {
  __shared__ float Cs[16][132];
  __shared__ float Bs2[16][132];
  int ig = blockIdx.x, bc = blockIdx.y;
  int t0 = bc * 256, i0 = ig * 16;
  int tid = threadIdx.x;
  {
    int e = tid * 8;
    int r = e >> 7, c = e & 127;
    *reinterpret_cast<float4*>(&Cs[r][c]) =
        *reinterpret_cast<const float4*>(&Cf[(long)(t0 + i0 + r) * 128 + c]);
    *reinterpret_cast<float4*>(&Cs[r][c + 4]) =
        *reinterpret_cast<const float4*>(&Cf[(long)(t0 + i0 + r) * 128 + c + 4]);
  }
  int ii = tid >> 4, jj = tid & 15;
  for (int jt = 0; jt < 16; ++jt) {
    __syncthreads();
    {
      int e = tid * 8;
      int r = e >> 7, c = e & 127;
      *reinterpret_cast<float4*>(&Bs2[r][c]) =
          *reinterpret_cast<const float4*>(&Bf[(long)(t0 + jt * 16 + r) * 128 + c]);
      *reinterpret_cast<float4*>(&Bs2[r][c + 4]) =
          *reinterpret_cast<const float4*>(&Bf[(long)(t0 + jt * 16 + r) * 128 + c + 4]);
    }
    __syncthreads();
    float acc = 0.f;
#pragma unroll
    for (int n = 0; n < 128; n += 4) {
      float4 cv = *reinterpret_cast<const float4*>(&Cs[ii][n]);
      float4 bv = *reinterpret_cast<const float4*>(&Bs2[jj][n]);
      acc = fmaf(cv.x, bv.x, acc);
      acc = fmaf(cv.y, bv.y, acc);
      acc = fmaf(cv.z, bv.z, acc);
      acc = fmaf(cv.w, bv.w, acc);
    }
    CBT[(long)bc * 65536 + (long)(i0 + ii) * 256 + jt * 16 + jj] = acc;
  }
}

// ------------------------------------------------- states[bc,h,p,n] (64x128)
__global__ __launch_bounds__(256) void states_kernel(const float* __restrict__ xf,
                                                     const float* __restrict__ Bf,
                                                     const float* __restrict__ dt_f,
                                                     const float* __restrict__ cum_f,
                                                     const float* __restrict__ cuml,
                                                     float* __restrict__ states) {
  int h = blockIdx.x, bc = blockIdx.y;
  int t0 = bc * 256;
  int tid = threadIdx.x;
  __shared__ float w_s[256];
  __shared__ float xw[16][64];
  __shared__ float Bs_[16][128];
  {
    int t = t0 + tid;
    w_s[tid] = expf(cuml[bc * 64 + h] - cum_f[(long)t * 64 + h]) * dt_f[(long)t * 64 + h];
  }
  int tx = tid & 15, ty = tid >> 4;
  float acc[4][8];
#pragma unroll
  for (int i = 0; i < 4; i++)
#pragma unroll
    for (int j = 0; j < 8; j++) acc[i][j] = 0.f;
  __syncthreads();
  for (int lt = 0; lt < 16; ++lt) {
    {
      int e = tid * 4;
      int ll = e >> 6, p = e & 63;
      float wv = w_s[lt * 16 + ll];
      float4 xv = *reinterpret_cast<const float4*>(
          &xf[(long)(t0 + lt * 16 + ll) * 4096 + h * 64 + p]);
      xw[ll][p] = xv.x * wv; xw[ll][p + 1] = xv.y * wv;
      xw[ll][p + 2] = xv.z * wv; xw[ll][p + 3] = xv.w * wv;
      int ll2 = tid >> 4; int n = (tid & 15) * 8;
      const float* pb = Bf + (long)(t0 + lt * 16 + ll2) * 128 + n;
      *reinterpret_cast<float4*>(&Bs_[ll2][n]) = *reinterpret_cast<const float4*>(pb);
      *reinterpret_cast<float4*>(&Bs_[ll2][n + 4]) = *reinterpret_cast<const float4*>(pb + 4);
    }
    __syncthreads();
#pragma unroll
    for (int ll = 0; ll < 16; ++ll) {
      float4 xv = *reinterpret_cast<float4*>(&xw[ll][ty * 4]);
      float4 b0 = *reinterpret_cast<float4*>(&Bs_[ll][tx * 8]);
      float4 b1 = *reinterpret_cast<float4*>(&Bs_[ll][tx * 8 + 4]);
      float xi[4] = {xv.x, xv.y, xv.z, xv.w};
      float bb[8] = {b0.x, b0.y, b0.z, b0.w, b1.x, b1.y, b1.z, b1.w};
#pragma unroll
      for (int i = 0; i < 4; i++)
#pragma unroll
        for (int j = 0; j < 8; j++) acc[i][j] = fmaf(xi[i], bb[j], acc[i][j]);
    }
    __syncthreads();
  }
  long base = (long)(bc * 64 + h) * 8192 + (long)(ty * 4) * 128 + tx * 8;
#pragma unroll
  for (int i = 0; i < 4; i++) {
    float4 v0 = {acc[i][0], acc[i][1], acc[i][2], acc[i][3]};
    float4 v1 = {acc[i][4], acc[i][5], acc[i][6], acc[i][7]};
    *reinterpret_cast<float4*>(&states[base + i * 128]) = v0;
    *reinterpret_cast<float4*>(&states[base + i * 128 + 4]) = v1;
  }
}

// --------------------------------- inter-chunk recurrence (in-place -> prevs)
__global__ __launch_bounds__(256) void recur_kernel(float* __restrict__ states,
                                                    const float* __restrict__ cuml) {
  int bh = blockIdx.x;
  int b = bh >> 6, h = bh & 63;
  int tid = threadIdx.x;
  float4 prev[8];
#pragma unroll
  for (int j = 0; j < 8; j++) prev[j] = make_float4(0.f, 0.f, 0.f, 0.f);
  for (int c = 0; c < 8; c++) {
    int bc = b * 8 + c;
    float cd = expf(cuml[bc * 64 + h]);
    long base = (long)(bc * 64 + h) * 8192;
#pragma unroll
    for (int j = 0; j < 8; j++) {
      long o = base + j * 1024 + tid * 4;
      float4 st = *reinterpret_cast<const float4*>(&states[o]);
      *reinterpret_cast<float4*>(&states[o]) = prev[j];
      prev[j].x = fmaf(cd, prev[j].x, st.x);
      prev[j].y = fmaf(cd, prev[j].y, st.y);
      prev[j].z = fmaf(cd, prev[j].z, st.z);
      prev[j].w = fmaf(cd, prev[j].w, st.w);
    }
  }
}

// ------------------------------------------------- Y_diag (intra-chunk)
__global__ __launch_bounds__(256) void ydiag_kernel(const float* __restrict__ xf,
                                                    const float* __restrict__ CBT,
                                                    const float* __restrict__ dt_f,
                                                    const float* __restrict__ cum_f,
                                                    float* __restrict__ Ysum) {
  int h = blockIdx.x, bc = blockIdx.y;
  int t0 = bc * 256;
  int i = threadIdx.x;
  __shared__ float xs[128][64];
  __shared__ float cum_s[256];
  __shared__ float dt_s[256];
  cum_s[i] = cum_f[(long)(t0 + i) * 64 + h];
  dt_s[i] = dt_f[(long)(t0 + i) * 64 + h];
  float cum_i = cum_s[i];
  const float* cbrow = CBT + (long)bc * 65536 + (long)i * 256;
  float acc_[64];
#pragma unroll
  for (int p = 0; p < 64; p++) acc_[p] = 0.f;
  for (int half = 0; half < 2; ++half) {
    __syncthreads();
#pragma unroll
    for (int k = 0; k < 8; k++) {
      int e = i * 4 + k * 1024;
      int ll = e >> 6, p = e & 63;
      *reinterpret_cast<float4*>(&xs[ll][p]) = *reinterpret_cast<const float4*>(
          &xf[(long)(t0 + half * 128 + ll) * 4096 + h * 64 + p]);
    }
    __syncthreads();
    int jlo = half * 128;
    int jhi = (jlo + 128 < i + 1) ? (jlo + 128) : (i + 1);
    for (int j = jlo; j < jhi; ++j) {
      float s = cbrow[j] * expf(cum_i - cum_s[j]) * dt_s[j];
      const float* xr = &xs[j - jlo][0];
#pragma unroll
      for (int p4 = 0; p4 < 16; p4++) {
        float4 xv = *reinterpret_cast<const float4*>(xr + p4 * 4);
        acc_[p4 * 4 + 0] = fmaf(s, xv.x, acc_[p4 * 4 + 0]);
        acc_[p4 * 4 + 1] = fmaf(s, xv.y, acc_[p4 * 4 + 1]);
        acc_[p4 * 4 + 2] = fmaf(s, xv.z, acc_[p4 * 4 + 2]);
        acc_[p4 * 4 + 3] = fmaf(s, xv.w, acc_[p4 * 4 + 3]);
      }
    }
  }
  float* yr = Ysum + (long)(t0 + i) * 4096 + h * 64;
#pragma unroll
  for (int p4 = 0; p4 < 16; p4++) {
    float4 v = {acc_[p4 * 4 + 0], acc_[p4 * 4 + 1], acc_[p4 * 4 + 2], acc_[p4 * 4 + 3]};
    *reinterpret_cast<float4*>(yr + p4 * 4) = v;
  }
}

// ------------------------------------------------- Y_off + D*x  (+= Ysum)
__global__ __launch_bounds__(256) void yoff_kernel(const float* __restrict__ xf,
                                                   const float* __restrict__ Cf,
                                                   const float* __restrict__ prevs,
                                                   const float* __restrict__ cum_f,
                                                   const float* __restrict__ Dp,
                                                   float* __restrict__ Ysum) {
  int h = blockIdx.x, bc = blockIdx.y;
  int t0 = bc * 256;
  int i = threadIdx.x;
  __shared__ float PSf[8192];  // [p][n] 64x128
#pragma unroll
  for (int k = 0; k < 8; k++) {
    int e = i * 4 + k * 1024;
    *reinterpret_cast<float4*>(&PSf[e]) =
        *reinterpret_cast<const float4*>(&prevs[(long)(bc * 64 + h) * 8192 + e]);
  }
  __syncthreads();
  float acc_[64];
#pragma unroll
  for (int p = 0; p < 64; p++) acc_[p] = 0.f;
  const float* crow = Cf + (long)(t0 + i) * 128;
  for (int nt = 0; nt < 16; ++nt) {
    float4 c0 = *reinterpret_cast<const float4*>(crow + nt * 8);
    float4 c1 = *reinterpret_cast<const float4*>(crow + nt * 8 + 4);
    float cv[8] = {c0.x, c0.y, c0.z, c0.w, c1.x, c1.y, c1.z, c1.w};
#pragma unroll
    for (int p = 0; p < 64; p++) {
      const float* ps = &PSf[p * 128 + nt * 8];
      float4 pa = *reinterpret_cast<const float4*>(ps);
      float4 pb = *reinterpret_cast<const float4*>(ps + 4);
      float t = fmaf(cv[0], pa.x, fmaf(cv[1], pa.y, fmaf(cv[2], pa.z, cv[3] * pa.w)));
      t = fmaf(cv[4], pb.x, fmaf(cv[5], pb.y, fmaf(cv[6], pb.z, fmaf(cv[7], pb.w, t))));
      acc_[p] += t;
    }
  }
  float fac = expf(cum_f[(long)(t0 + i) * 64 + h]);
  float Dh = Dp[h];
  const float* xrow = xf + (long)(t0 + i) * 4096 + h * 64;
  float* yr = Ysum + (long)(t0 + i) * 4096 + h * 64;
#pragma unroll
  for (int p4 = 0; p4 < 16; p4++) {
    float4 y = *reinterpret_cast<float4*>(yr + p4 * 4);
    float4 xv = *reinterpret_cast<const float4*>(xrow + p4 * 4);
    y.x += acc_[p4 * 4 + 0] * fac + Dh * xv.x;
    y.y += acc_[p4 * 4 + 1] * fac + Dh * xv.y;
    y.z += acc_[p4 * 4 + 2] * fac + Dh * xv.z;
    y.w += acc_[p4 * 4 + 3] * fac + Dh * xv.w;
    *reinterpret_cast<float4*>(yr + p4 * 4) = y;
  }
}

// ------------------------------------------------- gate*SiLU + RMSNorm -> bf16
__global__ __launch_bounds__(256) void norm_kernel(const float* __restrict__ Ysum,
                                                   const BF16* __restrict__ gate,
                                                   const float* __restrict__ nw,
                                                   BF16* __restrict__ hid) {
  int t = blockIdx.x;
  int tid = threadIdx.x;
  float hv[16];
  float ss = 0.f;
#pragma unroll
  for (int k = 0; k < 4; k++) {
    int d = tid * 4 + k * 1024;
    float4 y = *reinterpret_cast<const float4*>(&Ysum[(long)t * 4096 + d]);
    float4 g = load4bf(gate + (long)t * 4096 + d);
    float h0 = y.x * siluf(g.x), h1 = y.y * siluf(g.y);
    float h2 = y.z * siluf(g.z), h3 = y.w * siluf(g.w);
    hv[k * 4 + 0] = h0; hv[k * 4 + 1] = h1; hv[k * 4 + 2] = h2; hv[k * 4 + 3] = h3;
    ss += h0 * h0 + h1 * h1 + h2 * h2 + h3 * h3;
  }
#pragma unroll
  for (int o = 32; o > 0; o >>= 1) ss += __shfl_down(ss, o, 64);
  __shared__ float ws4[4];
  if ((tid & 63) == 0) ws4[tid >> 6] = ss;
  __syncthreads();
  float var = (ws4[0] + ws4[1] + ws4[2] + ws4[3]) * (1.f / 4096.f);
  float scale = rsqrtf(var + 1e-5f);
#pragma unroll
  for (int k = 0; k < 4; k++) {
    int d = tid * 4 + k * 1024;
    ushort4 u;
#pragma unroll
    for (int c = 0; c < 4; c++)
      ((unsigned short*)&u)[c] = f2bfu(hv[k * 4 + c] * scale * nw[d + c]);
    *reinterpret_cast<ushort4*>(hid + (long)t * 4096 + d) = u;
  }
}

// =============================================================== launch
extern "C" void kernel_launch(void* const* d_in, const int* in_sizes, int n_in,
                              void* d_out, int out_size, void* d_ws, size_t ws_size,
                              hipStream_t stream) {
  (void)in_sizes; (void)n_in; (void)out_size; (void)ws_size;
  const float* hs    = (const float*)d_in[0];
  const float* Win   = (const float*)d_in[1];
  const float* convw = (const float*)d_in[2];
  const float* convb = (const float*)d_in[3];
  const float* dtb   = (const float*)d_in[4];
  const float* Alog  = (const float*)d_in[5];
  const float* Dp    = (const float*)d_in[6];
  const float* nw    = (const float*)d_in[7];
  const float* Wout  = (const float*)d_in[8];
  float* out = (float*)d_out;

  char* base = (char*)d_ws;
  size_t off = 0;
  auto take = [&](size_t n) { char* r = base + off; off += (n + 255) & ~(size_t)255; return r; };
  float* hbcf  = (float*)take(4096UL * 4352 * 4);  // gemm3 -> conv; then Ysum
  BF16* gateb  = (BF16*)take(4096UL * 4096 * 2);   // gemm3 -> norm
  BF16* Ahi    = (BF16*)take(4096UL * 2048 * 2);   // cast -> gemm3; then WoutT
  BF16* Alo    = (BF16*)take(4096UL * 2048 * 2);   // cast -> gemm3
  BF16* WtHi   = (BF16*)take(8448UL * 2048 * 2);   // trans -> gemm3; then xf
  BF16* WtLo   = (BF16*)take(8448UL * 2048 * 2);   //   (xf spans WtHi+WtLo)
  float* zf    = (float*)take(4096UL * 64 * 4);
  float* dt_f  = (float*)take(4096UL * 64 * 4);
  float* cum_f = (float*)take(4096UL * 64 * 4);
  float* cuml  = (float*)take(16UL * 64 * 4);
  float* Bf    = (float*)take(4096UL * 128 * 4);
  float* Cf    = (float*)take(4096UL * 128 * 4);
  float* CBT   = (float*)take(16UL * 256 * 256 * 4);
  float* states= (float*)take(1024UL * 8192 * 4);  // -> prevs in-place; then hid
  // overlays on dead regions:
  float* Ysum  = hbcf;          // 67.1MB in 71.3MB region, live ydiag..norm
  BF16*  WoutT = Ahi;           // 16.8MB exact, written after gemm3
  float* xf    = (float*)WtHi;  // 67.1MB in 69.2MB region, live conv..yoff
  BF16*  hid   = (BF16*)states; // 33.6MB exact, live norm..out_proj
  (void)Alo; (void)WtLo;

  dim3 tb(32, 8);
  // 1. split-cast X, split-transpose Win cols [0,8448)
  cast_split<<<8192, 256, 0, stream>>>(hs, Ahi, Alo);
  transpose_split<<<dim3(264, 64), tb, 0, stream>>>(Win, WtHi, WtLo);
  // 2. exact fp32 dt pre-activation (cols 8448..8512)
  dtz_kernel<<<1024, 256, 0, stream>>>(hs, Win, zf);
  // 3. split in_proj GEMM -> gate (bf16) + hbc (fp32)
  gemm_split<<<dim3(66, 32), 256, 0, stream>>>(Ahi, Alo, WtHi, WtLo, gateb, hbcf);
  // 4. transpose out_proj into dead Ahi region
  transpose_cast<<<dim3(64, 128), tb, 0, stream>>>(Wout, WoutT, 4096, 2048);
  // 5. conv + silu (fp32) -> x, B, C
  conv_silu_kernel<<<dim3(17, 4096), 256, 0, stream>>>(hbcf, convw, convb, xf, Bf, Cf);
  // 6. dt softplus + cumsum (fp32-exact)
  dt_cum_kernel<<<16, 256, 0, stream>>>(zf, dtb, Alog, dt_f, cum_f, cuml);
  // 7. C.B^T per chunk, fp32 VALU
  cbt_kernel<<<dim3(16, 16), 256, 0, stream>>>(Cf, Bf, CBT);
  // 8. per-chunk states (fp32)
  states_kernel<<<dim3(64, 16), 256, 0, stream>>>(xf, Bf, dt_f, cum_f, cuml, states);
  // 9. inter-chunk recurrence (in-place)
  recur_kernel<<<128, 256, 0, stream>>>(states, cuml);
  // 10. Y_diag (Ysum overlays dead hbcf)
  ydiag_kernel<<<dim3(64, 16), 256, 0, stream>>>(xf, CBT, dt_f, cum_f, Ysum);
  // 11. Y_off + D*x
  yoff_kernel<<<dim3(64, 16), 256, 0, stream>>>(xf, Cf, states, cum_f, Dp, Ysum);
  // 12. gate + RMSNorm -> hid bf16 (overlays dead states)
  norm_kernel<<<4096, 256, 0, stream>>>(Ysum, gateb, nw, hid);
  // 13. out_proj GEMM -> d_out fp32
  gemm_bt<<<dim3(16, 32), 256, 0, stream>>>(hid, WoutT, out, 4096, 2048);
}

// Round 5
// 1109.541 us; speedup vs baseline: 1.2269x; 1.2269x over previous
//
#include <hip/hip_runtime.h>
#include <hip/hip_bf16.h>

// Mamba2 mixer forward, MI355X. B=2, L=2048, D_MODEL=2048, H=64, P=64, N=128,
// G=1, K=4, CHUNK=256. T = 4096 tokens, 16 chunks.
// Precision plan: fp16 in_proj GEMM (11-bit mantissa, same MFMA rate as bf16)
// -> fp32 hbc -> fp32 conv -> fp32 scan -> fp16 gate/hid/out_proj GEMM.

typedef __attribute__((ext_vector_type(8))) _Float16 f16x8;
typedef __attribute__((ext_vector_type(4))) float f32x4;

#define GLD16(gp, lp) __builtin_amdgcn_global_load_lds( \
    (__attribute__((address_space(1))) void*)(gp),      \
    (__attribute__((address_space(3))) void*)(lp), 16, 0, 0)

__device__ __forceinline__ unsigned short f2hu(float v) {
  _Float16 h = (_Float16)v;
  return *reinterpret_cast<unsigned short*>(&h);
}
__device__ __forceinline__ float4 load4h(const _Float16* p) {
  ushort4 u = *reinterpret_cast<const ushort4*>(p);
  float4 r;
  r.x = (float)(*reinterpret_cast<_Float16*>(&u.x));
  r.y = (float)(*reinterpret_cast<_Float16*>(&u.y));
  r.z = (float)(*reinterpret_cast<_Float16*>(&u.z));
  r.w = (float)(*reinterpret_cast<_Float16*>(&u.w));
  return r;
}
__device__ __forceinline__ float siluf(float x) { return x / (1.f + expf(-x)); }

// ---------------------------------------------------------------- cast X->fp16
__global__ __launch_bounds__(256) void cast_f16(const float* __restrict__ s,
                                                _Float16* __restrict__ d) {
  long i = ((long)blockIdx.x * 256 + threadIdx.x) * 4;
  float4 v = *reinterpret_cast<const float4*>(s + i);
  ushort4 u;
  u.x = f2hu(v.x); u.y = f2hu(v.y); u.z = f2hu(v.z); u.w = f2hu(v.w);
  *reinterpret_cast<ushort4*>(d + i) = u;
}

// --------------------------- transpose Win cols [0,8448) -> fp16 [n][k]
__global__ __launch_bounds__(256) void transpose_win(const float* __restrict__ src,
                                                     _Float16* __restrict__ dst) {
  __shared__ float tile[32][33];
  int c0 = blockIdx.x * 32, r0 = blockIdx.y * 32;  // c: [0,8448), r: [0,2048)
  int tx = threadIdx.x, ty = threadIdx.y;          // 32 x 8
#pragma unroll
  for (int i = 0; i < 4; i++)
    tile[ty + i * 8][tx] = src[(long)(r0 + ty + i * 8) * 8512 + c0 + tx];
  __syncthreads();
#pragma unroll
  for (int i = 0; i < 4; i++) {
    int c = c0 + ty + i * 8, r = r0 + tx;
    dst[(long)c * 2048 + r] = (_Float16)tile[tx][ty + i * 8];
  }
}

// ------------------ transpose+cast fp32 RxC -> fp16 [C][R] (for out_proj W)
__global__ __launch_bounds__(256) void transpose_wout(const float* __restrict__ src,
                                                      _Float16* __restrict__ dst,
                                                      int R, int C) {
  __shared__ float tile[32][33];
  int c0 = blockIdx.x * 32, r0 = blockIdx.y * 32;
  int tx = threadIdx.x, ty = threadIdx.y;
#pragma unroll
  for (int i = 0; i < 4; i++)
    tile[ty + i * 8][tx] = src[(long)(r0 + ty + i * 8) * C + c0 + tx];
  __syncthreads();
#pragma unroll
  for (int i = 0; i < 4; i++) {
    int c = c0 + ty + i * 8, r = r0 + tx;
    dst[(long)c * R + r] = (_Float16)tile[tx][ty + i * 8];
  }
}

// ------------------------------- fp16 in_proj GEMM: A[4096,2048]*W[8448,2048]^T
// cols <4096 -> gate (fp16), cols >=4096 -> hbcf (fp32, ldc 4352).
__global__ __launch_bounds__(256) void gemm_in(const _Float16* __restrict__ A,
                                               const _Float16* __restrict__ Bt,
                                               _Float16* __restrict__ gate,
                                               float* __restrict__ hbcf) {
  __shared__ uint4 As4[512];
  __shared__ uint4 Bs4[512];
  _Float16* As = (_Float16*)As4;
  _Float16* Bs = (_Float16*)Bs4;
  const int tid = threadIdx.x;
  const int wv = tid >> 6;
  const int lane = tid & 63;
  const _Float16* Ab = A + (long)blockIdx.y * 128 * 2048;
  const _Float16* Bb = Bt + (long)blockIdx.x * 128 * 2048;
  const int c0 = wv * 128 + lane;
  const int c1 = c0 + 64;
  const long ra0 = (long)(c0 >> 2) * 2048 + (c0 & 3) * 8;
  const long ra1 = (long)(c1 >> 2) * 2048 + (c1 & 3) * 8;
  f32x4 acc[4][4];
#pragma unroll
  for (int mi = 0; mi < 4; mi++)
#pragma unroll
    for (int ni = 0; ni < 4; ni++) acc[mi][ni] = f32x4{0.f, 0.f, 0.f, 0.f};
  const int mrow = (wv & 1) * 64 + (lane & 15);
  const int nrow = (wv >> 1) * 64 + (lane & 15);
  const int koff = (lane >> 4) * 8;
  for (int k0 = 0; k0 < 2048; k0 += 32) {
    GLD16(Ab + ra0 + k0, (char*)As + c0 * 16);
    GLD16(Ab + ra1 + k0, (char*)As + c1 * 16);
    GLD16(Bb + ra0 + k0, (char*)Bs + c0 * 16);
    GLD16(Bb + ra1 + k0, (char*)Bs + c1 * 16);
    __syncthreads();
    f16x8 af[4], bfr[4];
#pragma unroll
    for (int mi = 0; mi < 4; mi++)
      af[mi] = *(const f16x8*)(As + (mrow + mi * 16) * 32 + koff);
#pragma unroll
    for (int ni = 0; ni < 4; ni++)
      bfr[ni] = *(const f16x8*)(Bs + (nrow + ni * 16) * 32 + koff);
#pragma unroll
    for (int mi = 0; mi < 4; mi++)
#pragma unroll
      for (int ni = 0; ni < 4; ni++)
        acc[mi][ni] = __builtin_amdgcn_mfma_f32_16x16x32_f16(af[mi], bfr[ni],
                                                             acc[mi][ni], 0, 0, 0);
    __syncthreads();
  }
  const int m0 = blockIdx.y * 128 + (wv & 1) * 64;
  const int n0 = blockIdx.x * 128 + (wv >> 1) * 64;
  const int cl = lane & 15, rq = (lane >> 4) * 4;
  if (n0 < 4096) {
#pragma unroll
    for (int mi = 0; mi < 4; mi++)
#pragma unroll
      for (int r = 0; r < 4; r++) {
        long rowoff = (long)(m0 + mi * 16 + rq + r) * 4096 + n0 + cl;
#pragma unroll
        for (int ni = 0; ni < 4; ni++)
          gate[rowoff + ni * 16] = (_Float16)acc[mi][ni][r];
      }
  } else {
#pragma unroll
    for (int mi = 0; mi < 4; mi++)
#pragma unroll
      for (int r = 0; r < 4; r++) {
        long rowoff = (long)(m0 + mi * 16 + rq + r) * 4352 + (n0 - 4096) + cl;
#pragma unroll
        for (int ni = 0; ni < 4; ni++) hbcf[rowoff + ni * 16] = acc[mi][ni][r];
      }
  }
}

// ------------------------------------------------------------- fp16 GEMM (B^T)
// out[M,N] fp32 = A[M,K] * Bt[N,K]^T.  (used for out_proj)
__global__ __launch_bounds__(256) void gemm_bt(const _Float16* __restrict__ A,
                                               const _Float16* __restrict__ Bt,
                                               float* __restrict__ Cf,
                                               int K, int ldc) {
  __shared__ uint4 As4[512];
  __shared__ uint4 Bs4[512];
  _Float16* As = (_Float16*)As4;
  _Float16* Bs = (_Float16*)Bs4;
  const int tid = threadIdx.x;
  const int wv = tid >> 6;
  const int lane = tid & 63;
  const _Float16* Ab = A + (long)blockIdx.y * 128 * K;
  const _Float16* Bb = Bt + (long)blockIdx.x * 128 * K;
  const int c0 = wv * 128 + lane;
  const int c1 = c0 + 64;
  const long ra0 = (long)(c0 >> 2) * K + (c0 & 3) * 8;
  const long ra1 = (long)(c1 >> 2) * K + (c1 & 3) * 8;
  f32x4 acc[4][4];
#pragma unroll
  for (int mi = 0; mi < 4; mi++)
#pragma unroll
    for (int ni = 0; ni < 4; ni++) acc[mi][ni] = f32x4{0.f, 0.f, 0.f, 0.f};
  const int mrow = (wv & 1) * 64 + (lane & 15);
  const int nrow = (wv >> 1) * 64 + (lane & 15);
  const int koff = (lane >> 4) * 8;
  for (int k0 = 0; k0 < K; k0 += 32) {
    GLD16(Ab + ra0 + k0, (char*)As + c0 * 16);
    GLD16(Ab + ra1 + k0, (char*)As + c1 * 16);
    GLD16(Bb + ra0 + k0, (char*)Bs + c0 * 16);
    GLD16(Bb + ra1 + k0, (char*)Bs + c1 * 16);
    __syncthreads();
    f16x8 af[4], bfr[4];
#pragma unroll
    for (int mi = 0; mi < 4; mi++)
      af[mi] = *(const f16x8*)(As + (mrow + mi * 16) * 32 + koff);
#pragma unroll
    for (int ni = 0; ni < 4; ni++)
      bfr[ni] = *(const f16x8*)(Bs + (nrow + ni * 16) * 32 + koff);
#pragma unroll
    for (int mi = 0; mi < 4; mi++)
#pragma unroll
      for (int ni = 0; ni < 4; ni++)
        acc[mi][ni] = __builtin_amdgcn_mfma_f32_16x16x32_f16(af[mi], bfr[ni],
                                                             acc[mi][ni], 0, 0, 0);
    __syncthreads();
  }
  const int m0 = blockIdx.y * 128 + (wv & 1) * 64;
  const int n0 = blockIdx.x * 128 + (wv >> 1) * 64;
  const int cl = lane & 15, rq = (lane >> 4) * 4;
#pragma unroll
  for (int mi = 0; mi < 4; mi++)
#pragma unroll
    for (int r = 0; r < 4; r++) {
      long rowoff = (long)(m0 + mi * 16 + rq + r) * ldc + n0 + cl;
#pragma unroll
      for (int ni = 0; ni < 4; ni++) Cf[rowoff + ni * 16] = acc[mi][ni][r];
    }
}

// ---------------------------------------- fp32 dt pre-activation (exact slice)
__global__ __launch_bounds__(256) void dtz_kernel(const float* __restrict__ hs,
                                                  const float* __restrict__ Win,
                                                  float* __restrict__ zf) {
  __shared__ float Xs[4][2048];
  int t0 = blockIdx.x * 4;
  int tid = threadIdx.x;
#pragma unroll
  for (int i = 0; i < 8; i++) {
    int e = tid * 4 + i * 1024;
    int tok = e >> 11, k = e & 2047;
    *reinterpret_cast<float4*>(&Xs[tok][k]) =
        *reinterpret_cast<const float4*>(&hs[(long)(t0 + tok) * 2048 + k]);
  }
  __syncthreads();
  int h = tid & 63, tg = tid >> 6;
  float a0 = 0.f, a1 = 0.f, a2 = 0.f, a3 = 0.f;
  const float* wcol = Win + 8448 + h;
  for (int k = 0; k < 2048; k += 4) {
    a0 = fmaf(Xs[tg][k + 0], wcol[(long)(k + 0) * 8512], a0);
    a1 = fmaf(Xs[tg][k + 1], wcol[(long)(k + 1) * 8512], a1);
    a2 = fmaf(Xs[tg][k + 2], wcol[(long)(k + 2) * 8512], a2);
    a3 = fmaf(Xs[tg][k + 3], wcol[(long)(k + 3) * 8512], a3);
  }
  zf[(long)(t0 + tg) * 64 + h] = (a0 + a1) + (a2 + a3);
}

// ------------------------------------------------------ conv(K=4)+SiLU (fp32)
__global__ __launch_bounds__(256) void conv_silu_kernel(const float* __restrict__ hbcf,
                                                        const float* __restrict__ convw,
                                                        const float* __restrict__ convb,
                                                        float* __restrict__ xf,
                                                        float* __restrict__ Bf,
                                                        float* __restrict__ Cf) {
  int q = blockIdx.x * 256 + threadIdx.x;  // [0,4352)
  int t = blockIdx.y;                      // [0,4096)
  int l = t & 2047;
  const float* col = hbcf + (long)t * 4352 + q;
  float4 wq = *reinterpret_cast<const float4*>(convw + q * 4);
  float a = convb[q];
  if (l >= 3) a += col[-3 * 4352] * wq.x;
  if (l >= 2) a += col[-2 * 4352] * wq.y;
  if (l >= 1) a += col[-1 * 4352] * wq.z;
  a += col[0] * wq.w;
  float o = siluf(a);
  if (q < 4096) xf[(long)t * 4096 + q] = o;
  else if (q < 4224) Bf[(long)t * 128 + (q - 4096)] = o;
  else Cf[(long)t * 128 + (q - 4224)] = o;
}

// ------------------------------------------------- dt softplus + chunk cumsum
__global__ __launch_bounds__(256) void dt_cum_kernel(const float* __restrict__ zf,
                                                     const float* __restrict__ dtb,
                                                     const float* __restrict__ Alog,
                                                     float* __restrict__ dt_f,
                                                     float* __restrict__ cum_f,
                                                     float* __restrict__ cuml) {
  int bc = blockIdx.x;
  int h = threadIdx.x & 63, seg = threadIdx.x >> 6;
  int t0 = bc * 256;
  float Ah = -expf(Alog[h]);
  float bias = dtb[h];
  __shared__ float segsum[4][64];
  float s = 0.f;
  for (int j = 0; j < 64; j++) {
    int t = t0 + seg * 64 + j;
    float z = zf[(long)t * 64 + h] + bias;
    float v = (z > 20.f) ? z : log1pf(expf(z));
    dt_f[(long)t * 64 + h] = v;
    s += v * Ah;
  }
  segsum[seg][h] = s;
  __syncthreads();
  float run = 0.f;
  for (int k = 0; k < seg; k++) run += segsum[k][h];
  for (int j = 0; j < 64; j++) {
    int t = t0 + seg * 64 + j;
    run += dt_f[(long)t * 64 + h] * Ah;
    cum_f[(long)t * 64 + h] = run;
  }
  if (seg == 3) cuml[bc * 64 + h] = run;
}

// ------------------------------------------------- C.B^T per chunk, fp32 VALU
__global__ __launch_bounds__(256) void cbt_kernel(const float* __restrict__ Cf,
                                                  const float* __restrict__ Bf,
                                                  float* __restrict__ CBT) {
  __shared__ float Cs[16][132];
  __shared__ float Bs2[16][132];
  int ig = blockIdx.x, bc = blockIdx.y;
  int t0 = bc * 256, i0 = ig * 16;
  int tid = threadIdx.x;
  {
    int e = tid * 8;
    int r = e >> 7, c = e & 127;
    *reinterpret_cast<float4*>(&Cs[r][c]) =
        *reinterpret_cast<const float4*>(&Cf[(long)(t0 + i0 + r) * 128 + c]);
    *reinterpret_cast<float4*>(&Cs[r][c + 4]) =
        *reinterpret_cast<const float4*>(&Cf[(long)(t0 + i0 + r) * 128 + c + 4]);
  }
  int ii = tid >> 4, jj = tid & 15;
  for (int jt = 0; jt < 16; ++jt) {
    __syncthreads();
    {
      int e = tid * 8;
      int r = e >> 7, c = e & 127;
      *reinterpret_cast<float4*>(&Bs2[r][c]) =
          *reinterpret_cast<const float4*>(&Bf[(long)(t0 + jt * 16 + r) * 128 + c]);
      *reinterpret_cast<float4*>(&Bs2[r][c + 4]) =
          *reinterpret_cast<const float4*>(&Bf[(long)(t0 + jt * 16 + r) * 128 + c + 4]);
    }
    __syncthreads();
    float acc = 0.f;
#pragma unroll
    for (int n = 0; n < 128; n += 4) {
      float4 cv = *reinterpret_cast<const float4*>(&Cs[ii][n]);
      float4 bv = *reinterpret_cast<const float4*>(&Bs2[jj][n]);
      acc = fmaf(cv.x, bv.x, acc);
      acc = fmaf(cv.y, bv.y, acc);
      acc = fmaf(cv.z, bv.z, acc);
      acc = fmaf(cv.w, bv.w, acc);
    }
    CBT[(long)bc * 65536 + (long)(i0 + ii) * 256 + jt * 16 + jj] = acc;
  }
}

// ------------------------------------------------- states[bc,h,p,n] (64x128)
__global__ __launch_bounds__(256) void states_kernel(const float* __restrict__ xf,
                                                     const float* __restrict__ Bf,
                                                     const float* __restrict__ dt_f,
                                                     const float* __restrict__ cum_f,
                                                     const float* __restrict__ cuml,
                                                     float* __restrict__ states) {
  int h = blockIdx.x, bc = blockIdx.y;
  int t0 = bc * 256;
  int tid = threadIdx.x;
  __shared__ float w_s[256];
  __shared__ float xw[16][64];
  __shared__ float Bs_[16][128];
  {
    int t = t0 + tid;
    w_s[tid] = expf(cuml[bc * 64 + h] - cum_f[(long)t * 64 + h]) * dt_f[(long)t * 64 + h];
  }
  int tx = tid & 15, ty = tid >> 4;
  float acc[4][8];
#pragma unroll
  for (int i = 0; i < 4; i++)
#pragma unroll
    for (int j = 0; j < 8; j++) acc[i][j] = 0.f;
  __syncthreads();
  for (int lt = 0; lt < 16; ++lt) {
    {
      int e = tid * 4;
      int ll = e >> 6, p = e & 63;
      float wv = w_s[lt * 16 + ll];
      float4 xv = *reinterpret_cast<const float4*>(
          &xf[(long)(t0 + lt * 16 + ll) * 4096 + h * 64 + p]);
      xw[ll][p] = xv.x * wv; xw[ll][p + 1] = xv.y * wv;
      xw[ll][p + 2] = xv.z * wv; xw[ll][p + 3] = xv.w * wv;
      int ll2 = tid >> 4; int n = (tid & 15) * 8;
      const float* pb = Bf + (long)(t0 + lt * 16 + ll2) * 128 + n;
      *reinterpret_cast<float4*>(&Bs_[ll2][n]) = *reinterpret_cast<const float4*>(pb);
      *reinterpret_cast<float4*>(&Bs_[ll2][n + 4]) = *reinterpret_cast<const float4*>(pb + 4);
    }
    __syncthreads();
#pragma unroll
    for (int ll = 0; ll < 16; ++ll) {
      float4 xv = *reinterpret_cast<float4*>(&xw[ll][ty * 4]);
      float4 b0 = *reinterpret_cast<float4*>(&Bs_[ll][tx * 8]);
      float4 b1 = *reinterpret_cast<float4*>(&Bs_[ll][tx * 8 + 4]);
      float xi[4] = {xv.x, xv.y, xv.z, xv.w};
      float bb[8] = {b0.x, b0.y, b0.z, b0.w, b1.x, b1.y, b1.z, b1.w};
#pragma unroll
      for (int i = 0; i < 4; i++)
#pragma unroll
        for (int j = 0; j < 8; j++) acc[i][j] = fmaf(xi[i], bb[j], acc[i][j]);
    }
    __syncthreads();
  }
  long base = (long)(bc * 64 + h) * 8192 + (long)(ty * 4) * 128 + tx * 8;
#pragma unroll
  for (int i = 0; i < 4; i++) {
    float4 v0 = {acc[i][0], acc[i][1], acc[i][2], acc[i][3]};
    float4 v1 = {acc[i][4], acc[i][5], acc[i][6], acc[i][7]};
    *reinterpret_cast<float4*>(&states[base + i * 128]) = v0;
    *reinterpret_cast<float4*>(&states[base + i * 128 + 4]) = v1;
  }
}

// --------------------------------- inter-chunk recurrence (in-place -> prevs)
__global__ __launch_bounds__(256) void recur_kernel(float* __restrict__ states,
                                                    const float* __restrict__ cuml) {
  int bh = blockIdx.x;
  int b = bh >> 6, h = bh & 63;
  int tid = threadIdx.x;
  float4 prev[8];
#pragma unroll
  for (int j = 0; j < 8; j++) prev[j] = make_float4(0.f, 0.f, 0.f, 0.f);
  for (int c = 0; c < 8; c++) {
    int bc = b * 8 + c;
    float cd = expf(cuml[bc * 64 + h]);
    long base = (long)(bc * 64 + h) * 8192;
#pragma unroll
    for (int j = 0; j < 8; j++) {
      long o = base + j * 1024 + tid * 4;
      float4 st = *reinterpret_cast<const float4*>(&states[o]);
      *reinterpret_cast<float4*>(&states[o]) = prev[j];
      prev[j].x = fmaf(cd, prev[j].x, st.x);
      prev[j].y = fmaf(cd, prev[j].y, st.y);
      prev[j].z = fmaf(cd, prev[j].z, st.z);
      prev[j].w = fmaf(cd, prev[j].w, st.w);
    }
  }
}

// ------------------------------------------------- Y_diag (intra-chunk)
__global__ __launch_bounds__(256) void ydiag_kernel(const float* __restrict__ xf,
                                                    const float* __restrict__ CBT,
                                                    const float* __restrict__ dt_f,
                                                    const float* __restrict__ cum_f,
                                                    float* __restrict__ Ysum) {
  int h = blockIdx.x, bc = blockIdx.y;
  int t0 = bc * 256;
  int i = threadIdx.x;
  __shared__ float xs[128][64];
  __shared__ float cum_s[256];
  __shared__ float dt_s[256];
  cum_s[i] = cum_f[(long)(t0 + i) * 64 + h];
  dt_s[i] = dt_f[(long)(t0 + i) * 64 + h];
  float cum_i = cum_s[i];
  const float* cbrow = CBT + (long)bc * 65536 + (long)i * 256;
  float acc_[64];
#pragma unroll
  for (int p = 0; p < 64; p++) acc_[p] = 0.f;
  for (int half = 0; half < 2; ++half) {
    __syncthreads();
#pragma unroll
    for (int k = 0; k < 8; k++) {
      int e = i * 4 + k * 1024;
      int ll = e >> 6, p = e & 63;
      *reinterpret_cast<float4*>(&xs[ll][p]) = *reinterpret_cast<const float4*>(
          &xf[(long)(t0 + half * 128 + ll) * 4096 + h * 64 + p]);
    }
    __syncthreads();
    int jlo = half * 128;
    int jhi = (jlo + 128 < i + 1) ? (jlo + 128) : (i + 1);
    for (int j = jlo; j < jhi; ++j) {
      float s = cbrow[j] * expf(cum_i - cum_s[j]) * dt_s[j];
      const float* xr = &xs[j - jlo][0];
#pragma unroll
      for (int p4 = 0; p4 < 16; p4++) {
        float4 xv = *reinterpret_cast<const float4*>(xr + p4 * 4);
        acc_[p4 * 4 + 0] = fmaf(s, xv.x, acc_[p4 * 4 + 0]);
        acc_[p4 * 4 + 1] = fmaf(s, xv.y, acc_[p4 * 4 + 1]);
        acc_[p4 * 4 + 2] = fmaf(s, xv.z, acc_[p4 * 4 + 2]);
        acc_[p4 * 4 + 3] = fmaf(s, xv.w, acc_[p4 * 4 + 3]);
      }
    }
  }
  float* yr = Ysum + (long)(t0 + i) * 4096 + h * 64;
#pragma unroll
  for (int p4 = 0; p4 < 16; p4++) {
    float4 v = {acc_[p4 * 4 + 0], acc_[p4 * 4 + 1], acc_[p4 * 4 + 2], acc_[p4 * 4 + 3]};
    *reinterpret_cast<float4*>(yr + p4 * 4) = v;
  }
}

// ------------------------------------------------- Y_off + D*x  (+= Ysum)
__global__ __launch_bounds__(256) void yoff_kernel(const float* __restrict__ xf,
                                                   const float* __restrict__ Cf,
                                                   const float* __restrict__ prevs,
                                                   const float* __restrict__ cum_f,
                                                   const float* __restrict__ Dp,
                                                   float* __restrict__ Ysum) {
  int h = blockIdx.x, bc = blockIdx.y;
  int t0 = bc * 256;
  int i = threadIdx.x;
  __shared__ float PSf[8192];  // [p][n] 64x128
#pragma unroll
  for (int k = 0; k < 8; k++) {
    int e = i * 4 + k * 1024;
    *reinterpret_cast<float4*>(&PSf[e]) =
        *reinterpret_cast<const float4*>(&prevs[(long)(bc * 64 + h) * 8192 + e]);
  }
  __syncthreads();
  float acc_[64];
#pragma unroll
  for (int p = 0; p < 64; p++) acc_[p] = 0.f;
  const float* crow = Cf + (long)(t0 + i) * 128;
  for (int nt = 0; nt < 16; ++nt) {
    float4 c0 = *reinterpret_cast<const float4*>(crow + nt * 8);
    float4 c1 = *reinterpret_cast<const float4*>(crow + nt * 8 + 4);
    float cv[8] = {c0.x, c0.y, c0.z, c0.w, c1.x, c1.y, c1.z, c1.w};
#pragma unroll
    for (int p = 0; p < 64; p++) {
      const float* ps = &PSf[p * 128 + nt * 8];
      float4 pa = *reinterpret_cast<const float4*>(ps);
      float4 pb = *reinterpret_cast<const float4*>(ps + 4);
      float t = fmaf(cv[0], pa.x, fmaf(cv[1], pa.y, fmaf(cv[2], pa.z, cv[3] * pa.w)));
      t = fmaf(cv[4], pb.x, fmaf(cv[5], pb.y, fmaf(cv[6], pb.z, fmaf(cv[7], pb.w, t))));
      acc_[p] += t;
    }
  }
  float fac = expf(cum_f[(long)(t0 + i) * 64 + h]);
  float Dh = Dp[h];
  const float* xrow = xf + (long)(t0 + i) * 4096 + h * 64;
  float* yr = Ysum + (long)(t0 + i) * 4096 + h * 64;
#pragma unroll
  for (int p4 = 0; p4 < 16; p4++) {
    float4 y = *reinterpret_cast<float4*>(yr + p4 * 4);
    float4 xv = *reinterpret_cast<const float4*>(xrow + p4 * 4);
    y.x += acc_[p4 * 4 + 0] * fac + Dh * xv.x;
    y.y += acc_[p4 * 4 + 1] * fac + Dh * xv.y;
    y.z += acc_[p4 * 4 + 2] * fac + Dh * xv.z;
    y.w += acc_[p4 * 4 + 3] * fac + Dh * xv.w;
    *reinterpret_cast<float4*>(yr + p4 * 4) = y;
  }
}

// ------------------------------------------------- gate*SiLU + RMSNorm -> fp16
__global__ __launch_bounds__(256) void norm_kernel(const float* __restrict__ Ysum,
                                                   const _Float16* __restrict__ gate,
                                                   const float* __restrict__ nw,
                                                   _Float16* __restrict__ hid) {
  int t = blockIdx.x;
  int tid = threadIdx.x;
  float hv[16];
  float ss = 0.f;
#pragma unroll
  for (int k = 0; k < 4; k++) {
    int d = tid * 4 + k * 1024;
    float4 y = *reinterpret_cast<const float4*>(&Ysum[(long)t * 4096 + d]);
    float4 g = load4h(gate + (long)t * 4096 + d);
    float h0 = y.x * siluf(g.x), h1 = y.y * siluf(g.y);
    float h2 = y.z * siluf(g.z), h3 = y.w * siluf(g.w);
    hv[k * 4 + 0] = h0; hv[k * 4 + 1] = h1; hv[k * 4 + 2] = h2; hv[k * 4 + 3] = h3;
    ss += h0 * h0 + h1 * h1 + h2 * h2 + h3 * h3;
  }
#pragma unroll
  for (int o = 32; o > 0; o >>= 1) ss += __shfl_down(ss, o, 64);
  __shared__ float ws4[4];
  if ((tid & 63) == 0) ws4[tid >> 6] = ss;
  __syncthreads();
  float var = (ws4[0] + ws4[1] + ws4[2] + ws4[3]) * (1.f / 4096.f);
  float scale = rsqrtf(var + 1e-5f);
#pragma unroll
  for (int k = 0; k < 4; k++) {
    int d = tid * 4 + k * 1024;
    ushort4 u;
#pragma unroll
    for (int c = 0; c < 4; c++)
      ((unsigned short*)&u)[c] = f2hu(hv[k * 4 + c] * scale * nw[d + c]);
    *reinterpret_cast<ushort4*>(hid + (long)t * 4096 + d) = u;
  }
}

// =============================================================== launch
extern "C" void kernel_launch(void* const* d_in, const int* in_sizes, int n_in,
                              void* d_out, int out_size, void* d_ws, size_t ws_size,
                              hipStream_t stream) {
  (void)in_sizes; (void)n_in; (void)out_size; (void)ws_size;
  const float* hs    = (const float*)d_in[0];
  const float* Win   = (const float*)d_in[1];
  const float* convw = (const float*)d_in[2];
  const float* convb = (const float*)d_in[3];
  const float* dtb   = (const float*)d_in[4];
  const float* Alog  = (const float*)d_in[5];
  const float* Dp    = (const float*)d_in[6];
  const float* nw    = (const float*)d_in[7];
  const float* Wout  = (const float*)d_in[8];
  float* out = (float*)d_out;

  char* base = (char*)d_ws;
  size_t off = 0;
  auto take = [&](size_t n) { char* r = base + off; off += (n + 255) & ~(size_t)255; return r; };
  float*    hbcf  = (float*)take(4096UL * 4352 * 4);    // gemm_in -> conv; then Ysum
  _Float16* gateh = (_Float16*)take(4096UL * 4096 * 2); // gemm_in -> norm
  _Float16* Ah    = (_Float16*)take(4096UL * 2048 * 2); // cast -> gemm_in; then WoutT
  _Float16* WtH   = (_Float16*)take(8448UL * 2048 * 2); // trans -> gemm_in
  float*    xf    = (float*)take(4096UL * 4096 * 4);    // conv -> yoff
  float*    zf    = (float*)take(4096UL * 64 * 4);
  float*    dt_f  = (float*)take(4096UL * 64 * 4);
  float*    cum_f = (float*)take(4096UL * 64 * 4);
  float*    cuml  = (float*)take(16UL * 64 * 4);
  float*    Bf    = (float*)take(4096UL * 128 * 4);
  float*    Cf    = (float*)take(4096UL * 128 * 4);
  float*    CBT   = (float*)take(16UL * 256 * 256 * 4);
  float*    states= (float*)take(1024UL * 8192 * 4);    // -> prevs in-place; then hid
  // overlays on dead regions:
  float*    Ysum  = hbcf;               // 67.1MB in 71.3MB region, live ydiag..norm
  _Float16* WoutT = Ah;                 // 16.8MB exact, written after gemm_in
  _Float16* hid   = (_Float16*)states;  // 16.8MB in 33.6MB, live norm..out_proj

  dim3 tb(32, 8);
  // 1. cast X to fp16, transpose Win cols [0,8448) to fp16 [n][k]
  cast_f16<<<8192, 256, 0, stream>>>(hs, Ah);
  transpose_win<<<dim3(264, 64), tb, 0, stream>>>(Win, WtH);
  // 2. exact fp32 dt pre-activation (cols 8448..8512)
  dtz_kernel<<<1024, 256, 0, stream>>>(hs, Win, zf);
  // 3. fp16 in_proj GEMM -> gate (fp16) + hbc (fp32)
  gemm_in<<<dim3(66, 32), 256, 0, stream>>>(Ah, WtH, gateh, hbcf);
  // 4. transpose out_proj into dead Ah region (fp16)
  transpose_wout<<<dim3(64, 128), tb, 0, stream>>>(Wout, WoutT, 4096, 2048);
  // 5. conv + silu (fp32) -> x, B, C
  conv_silu_kernel<<<dim3(17, 4096), 256, 0, stream>>>(hbcf, convw, convb, xf, Bf, Cf);
  // 6. dt softplus + cumsum (fp32-exact)
  dt_cum_kernel<<<16, 256, 0, stream>>>(zf, dtb, Alog, dt_f, cum_f, cuml);
  // 7. C.B^T per chunk, fp32 VALU
  cbt_kernel<<<dim3(16, 16), 256, 0, stream>>>(Cf, Bf, CBT);
  // 8. per-chunk states (fp32)
  states_kernel<<<dim3(64, 16), 256, 0, stream>>>(xf, Bf, dt_f, cum_f, cuml, states);
  // 9. inter-chunk recurrence (in-place)
  recur_kernel<<<128, 256, 0, stream>>>(states, cuml);
  // 10. Y_diag (Ysum overlays dead hbcf)
  ydiag_kernel<<<dim3(64, 16), 256, 0, stream>>>(xf, CBT, dt_f, cum_f, Ysum);
  // 11. Y_off + D*x
  yoff_kernel<<<dim3(64, 16), 256, 0, stream>>>(xf, Cf, states, cum_f, Dp, Ysum);
  // 12. gate + RMSNorm -> hid fp16 (overlays dead states)
  norm_kernel<<<4096, 256, 0, stream>>>(Ysum, gateh, nw, hid);
  // 13. out_proj GEMM (fp16) -> d_out fp32
  gemm_bt<<<dim3(16, 32), 256, 0, stream>>>(hid, WoutT, out, 4096, 2048);
}

// Round 6
// 898.885 us; speedup vs baseline: 1.5144x; 1.2344x over previous
//
#include <hip/hip_runtime.h>
#include <hip/hip_bf16.h>

// Mamba2 mixer forward, MI355X. B=2, L=2048, D_MODEL=2048, H=64, P=64, N=128,
// G=1, K=4, CHUNK=256. T = 4096 tokens, 16 chunks.
// fp16 MFMA for: in_proj, CBT, states, ydiag+yoff (fused), out_proj.
// fp32 kept for: conv math, dt/cumsum (exact), inter-chunk recurrence, epilogues.

typedef __attribute__((ext_vector_type(8))) _Float16 f16x8;
typedef __attribute__((ext_vector_type(4))) float f32x4;

#define GLD16(gp, lp) __builtin_amdgcn_global_load_lds( \
    (__attribute__((address_space(1))) void*)(gp),      \
    (__attribute__((address_space(3))) void*)(lp), 16, 0, 0)

__device__ __forceinline__ unsigned short f2h(float v) {
  _Float16 h = (_Float16)v;
  return *reinterpret_cast<unsigned short*>(&h);
}
__device__ __forceinline__ float h2f(unsigned short u) {
  _Float16 h = *reinterpret_cast<_Float16*>(&u);
  return (float)h;
}
__device__ __forceinline__ float siluf(float x) { return x / (1.f + expf(-x)); }

// ---------------------------------------------------------------- cast X->fp16
__global__ __launch_bounds__(256) void cast_f16(const float* __restrict__ s,
                                                _Float16* __restrict__ d) {
  long i = ((long)blockIdx.x * 256 + threadIdx.x) * 4;
  float4 v = *reinterpret_cast<const float4*>(s + i);
  ushort4 u;
  u.x = f2h(v.x); u.y = f2h(v.y); u.z = f2h(v.z); u.w = f2h(v.w);
  *reinterpret_cast<ushort4*>(d + i) = u;
}

// --------------------------- transpose Win cols [0,8448) -> fp16 [n][k]
__global__ __launch_bounds__(256) void transpose_win(const float* __restrict__ src,
                                                     _Float16* __restrict__ dst) {
  __shared__ float tile[32][33];
  int c0 = blockIdx.x * 32, r0 = blockIdx.y * 32;
  int tx = threadIdx.x, ty = threadIdx.y;  // 32 x 8
#pragma unroll
  for (int i = 0; i < 4; i++)
    tile[ty + i * 8][tx] = src[(long)(r0 + ty + i * 8) * 8512 + c0 + tx];
  __syncthreads();
#pragma unroll
  for (int i = 0; i < 4; i++) {
    int c = c0 + ty + i * 8, r = r0 + tx;
    dst[(long)c * 2048 + r] = (_Float16)tile[tx][ty + i * 8];
  }
}

// ------------------ transpose+cast fp32 RxC -> fp16 [C][R] (for out_proj W)
__global__ __launch_bounds__(256) void transpose_wout(const float* __restrict__ src,
                                                      _Float16* __restrict__ dst,
                                                      int R, int C) {
  __shared__ float tile[32][33];
  int c0 = blockIdx.x * 32, r0 = blockIdx.y * 32;
  int tx = threadIdx.x, ty = threadIdx.y;
#pragma unroll
  for (int i = 0; i < 4; i++)
    tile[ty + i * 8][tx] = src[(long)(r0 + ty + i * 8) * C + c0 + tx];
  __syncthreads();
#pragma unroll
  for (int i = 0; i < 4; i++) {
    int c = c0 + ty + i * 8, r = r0 + tx;
    dst[(long)c * R + r] = (_Float16)tile[tx][ty + i * 8];
  }
}

// ------------------------------- fp16 in_proj GEMM: A[4096,2048]*W[8448,2048]^T
__global__ __launch_bounds__(256) void gemm_in(const _Float16* __restrict__ A,
                                               const _Float16* __restrict__ Bt,
                                               _Float16* __restrict__ gate,
                                               float* __restrict__ hbcf) {
  __shared__ uint4 As4[512];
  __shared__ uint4 Bs4[512];
  _Float16* As = (_Float16*)As4;
  _Float16* Bs = (_Float16*)Bs4;
  const int tid = threadIdx.x;
  const int wv = tid >> 6;
  const int lane = tid & 63;
  const _Float16* Ab = A + (long)blockIdx.y * 128 * 2048;
  const _Float16* Bb = Bt + (long)blockIdx.x * 128 * 2048;
  const int c0 = wv * 128 + lane;
  const int c1 = c0 + 64;
  const long ra0 = (long)(c0 >> 2) * 2048 + (c0 & 3) * 8;
  const long ra1 = (long)(c1 >> 2) * 2048 + (c1 & 3) * 8;
  f32x4 acc[4][4];
#pragma unroll
  for (int mi = 0; mi < 4; mi++)
#pragma unroll
    for (int ni = 0; ni < 4; ni++) acc[mi][ni] = f32x4{0.f, 0.f, 0.f, 0.f};
  const int mrow = (wv & 1) * 64 + (lane & 15);
  const int nrow = (wv >> 1) * 64 + (lane & 15);
  const int koff = (lane >> 4) * 8;
  for (int k0 = 0; k0 < 2048; k0 += 32) {
    GLD16(Ab + ra0 + k0, (char*)As + c0 * 16);
    GLD16(Ab + ra1 + k0, (char*)As + c1 * 16);
    GLD16(Bb + ra0 + k0, (char*)Bs + c0 * 16);
    GLD16(Bb + ra1 + k0, (char*)Bs + c1 * 16);
    __syncthreads();
    f16x8 af[4], bfr[4];
#pragma unroll
    for (int mi = 0; mi < 4; mi++)
      af[mi] = *(const f16x8*)(As + (mrow + mi * 16) * 32 + koff);
#pragma unroll
    for (int ni = 0; ni < 4; ni++)
      bfr[ni] = *(const f16x8*)(Bs + (nrow + ni * 16) * 32 + koff);
#pragma unroll
    for (int mi = 0; mi < 4; mi++)
#pragma unroll
      for (int ni = 0; ni < 4; ni++)
        acc[mi][ni] = __builtin_amdgcn_mfma_f32_16x16x32_f16(af[mi], bfr[ni],
                                                             acc[mi][ni], 0, 0, 0);
    __syncthreads();
  }
  const int m0 = blockIdx.y * 128 + (wv & 1) * 64;
  const int n0 = blockIdx.x * 128 + (wv >> 1) * 64;
  const int cl = lane & 15, rq = (lane >> 4) * 4;
  if (n0 < 4096) {
#pragma unroll
    for (int mi = 0; mi < 4; mi++)
#pragma unroll
      for (int r = 0; r < 4; r++) {
        long rowoff = (long)(m0 + mi * 16 + rq + r) * 4096 + n0 + cl;
#pragma unroll
        for (int ni = 0; ni < 4; ni++)
          gate[rowoff + ni * 16] = (_Float16)acc[mi][ni][r];
      }
  } else {
#pragma unroll
    for (int mi = 0; mi < 4; mi++)
#pragma unroll
      for (int r = 0; r < 4; r++) {
        long rowoff = (long)(m0 + mi * 16 + rq + r) * 4352 + (n0 - 4096) + cl;
#pragma unroll
        for (int ni = 0; ni < 4; ni++) hbcf[rowoff + ni * 16] = acc[mi][ni][r];
      }
  }
}

// --------------------------- fp16 GEMM (B^T), z-batched, fp32 out
// used for CBT (z=16, K=128) and out_proj (z=1, K=4096).
__global__ __launch_bounds__(256) void gemm_bt(const _Float16* __restrict__ A,
                                               const _Float16* __restrict__ Bt,
                                               float* __restrict__ Cf,
                                               int K, int ldc,
                                               long zsA, long zsB, long zsC) {
  __shared__ uint4 As4[512];
  __shared__ uint4 Bs4[512];
  _Float16* As = (_Float16*)As4;
  _Float16* Bs = (_Float16*)Bs4;
  const int tid = threadIdx.x;
  const int wv = tid >> 6;
  const int lane = tid & 63;
  const _Float16* Ab = A + (long)blockIdx.z * zsA + (long)blockIdx.y * 128 * K;
  const _Float16* Bb = Bt + (long)blockIdx.z * zsB + (long)blockIdx.x * 128 * K;
  const int c0 = wv * 128 + lane;
  const int c1 = c0 + 64;
  const long ra0 = (long)(c0 >> 2) * K + (c0 & 3) * 8;
  const long ra1 = (long)(c1 >> 2) * K + (c1 & 3) * 8;
  f32x4 acc[4][4];
#pragma unroll
  for (int mi = 0; mi < 4; mi++)
#pragma unroll
    for (int ni = 0; ni < 4; ni++) acc[mi][ni] = f32x4{0.f, 0.f, 0.f, 0.f};
  const int mrow = (wv & 1) * 64 + (lane & 15);
  const int nrow = (wv >> 1) * 64 + (lane & 15);
  const int koff = (lane >> 4) * 8;
  for (int k0 = 0; k0 < K; k0 += 32) {
    GLD16(Ab + ra0 + k0, (char*)As + c0 * 16);
    GLD16(Ab + ra1 + k0, (char*)As + c1 * 16);
    GLD16(Bb + ra0 + k0, (char*)Bs + c0 * 16);
    GLD16(Bb + ra1 + k0, (char*)Bs + c1 * 16);
    __syncthreads();
    f16x8 af[4], bfr[4];
#pragma unroll
    for (int mi = 0; mi < 4; mi++)
      af[mi] = *(const f16x8*)(As + (mrow + mi * 16) * 32 + koff);
#pragma unroll
    for (int ni = 0; ni < 4; ni++)
      bfr[ni] = *(const f16x8*)(Bs + (nrow + ni * 16) * 32 + koff);
#pragma unroll
    for (int mi = 0; mi < 4; mi++)
#pragma unroll
      for (int ni = 0; ni < 4; ni++)
        acc[mi][ni] = __builtin_amdgcn_mfma_f32_16x16x32_f16(af[mi], bfr[ni],
                                                             acc[mi][ni], 0, 0, 0);
    __syncthreads();
  }
  const int m0 = blockIdx.y * 128 + (wv & 1) * 64;
  const int n0 = blockIdx.x * 128 + (wv >> 1) * 64;
  const int cl = lane & 15, rq = (lane >> 4) * 4;
  const long zc = (long)blockIdx.z * zsC;
#pragma unroll
  for (int mi = 0; mi < 4; mi++)
#pragma unroll
    for (int r = 0; r < 4; r++) {
      long rowoff = zc + (long)(m0 + mi * 16 + rq + r) * ldc + n0 + cl;
#pragma unroll
      for (int ni = 0; ni < 4; ni++) Cf[rowoff + ni * 16] = acc[mi][ni][r];
    }
}

// ---------------------------------------- fp32 dt pre-activation (exact slice)
__global__ __launch_bounds__(256) void dtz_kernel(const float* __restrict__ hs,
                                                  const float* __restrict__ Win,
                                                  float* __restrict__ zf) {
  __shared__ float Xs[4][2048];
  int t0 = blockIdx.x * 4;
  int tid = threadIdx.x;
#pragma unroll
  for (int i = 0; i < 8; i++) {
    int e = tid * 4 + i * 1024;
    int tok = e >> 11, k = e & 2047;
    *reinterpret_cast<float4*>(&Xs[tok][k]) =
        *reinterpret_cast<const float4*>(&hs[(long)(t0 + tok) * 2048 + k]);
  }
  __syncthreads();
  int h = tid & 63, tg = tid >> 6;
  float a0 = 0.f, a1 = 0.f, a2 = 0.f, a3 = 0.f;
  const float* wcol = Win + 8448 + h;
  for (int k = 0; k < 2048; k += 4) {
    a0 = fmaf(Xs[tg][k + 0], wcol[(long)(k + 0) * 8512], a0);
    a1 = fmaf(Xs[tg][k + 1], wcol[(long)(k + 1) * 8512], a1);
    a2 = fmaf(Xs[tg][k + 2], wcol[(long)(k + 2) * 8512], a2);
    a3 = fmaf(Xs[tg][k + 3], wcol[(long)(k + 3) * 8512], a3);
  }
  zf[(long)(t0 + tg) * 64 + h] = (a0 + a1) + (a2 + a3);
}

// --------------------------- conv(K=4)+SiLU (fp32 math, fp16 out) -> x16,B16,C16
__global__ __launch_bounds__(256) void conv_silu_kernel(const float* __restrict__ hbcf,
                                                        const float* __restrict__ convw,
                                                        const float* __restrict__ convb,
                                                        _Float16* __restrict__ x16,
                                                        _Float16* __restrict__ B16,
                                                        _Float16* __restrict__ C16) {
  int q = blockIdx.x * 256 + threadIdx.x;  // [0,4352)
  int t = blockIdx.y;                      // [0,4096)
  int l = t & 2047;
  const float* col = hbcf + (long)t * 4352 + q;
  float4 wq = *reinterpret_cast<const float4*>(convw + q * 4);
  float a = convb[q];
  if (l >= 3) a += col[-3 * 4352] * wq.x;
  if (l >= 2) a += col[-2 * 4352] * wq.y;
  if (l >= 1) a += col[-1 * 4352] * wq.z;
  a += col[0] * wq.w;
  _Float16 o = (_Float16)siluf(a);
  if (q < 4096) x16[(long)t * 4096 + q] = o;
  else if (q < 4224) B16[(long)t * 128 + (q - 4096)] = o;
  else C16[(long)t * 128 + (q - 4224)] = o;
}

// ------------------------------------------- global transpose x16 -> xT16 [q][t]
__global__ __launch_bounds__(256) void xtrans(const unsigned short* __restrict__ src,
                                              unsigned short* __restrict__ dst) {
  __shared__ unsigned short tile[64][66];
  int c0 = blockIdx.x * 64, r0 = blockIdx.y * 64;
  int tx = threadIdx.x & 15, ty = threadIdx.x >> 4;  // 16 x 16
#pragma unroll
  for (int i = 0; i < 4; i++) {
    int r = ty + i * 16;
    ushort4 v = *(const ushort4*)&src[(long)(r0 + r) * 4096 + c0 + 4 * tx];
    tile[r][4 * tx] = v.x; tile[r][4 * tx + 1] = v.y;
    tile[r][4 * tx + 2] = v.z; tile[r][4 * tx + 3] = v.w;
  }
  __syncthreads();
#pragma unroll
  for (int i = 0; i < 4; i++) {
    int c = ty + i * 16;
    ushort4 v;
    v.x = tile[4 * tx + 0][c]; v.y = tile[4 * tx + 1][c];
    v.z = tile[4 * tx + 2][c]; v.w = tile[4 * tx + 3][c];
    *(ushort4*)&dst[(long)(c0 + c) * 4096 + r0 + 4 * tx] = v;
  }
}

// ------------------------------------------------- dt softplus + chunk cumsum
__global__ __launch_bounds__(256) void dt_cum_kernel(const float* __restrict__ zf,
                                                     const float* __restrict__ dtb,
                                                     const float* __restrict__ Alog,
                                                     float* __restrict__ dt_f,
                                                     float* __restrict__ cum_f,
                                                     float* __restrict__ cuml) {
  int bc = blockIdx.x;
  int h = threadIdx.x & 63, seg = threadIdx.x >> 6;
  int t0 = bc * 256;
  float Ah = -expf(Alog[h]);
  float bias = dtb[h];
  __shared__ float segsum[4][64];
  float s = 0.f;
  for (int j = 0; j < 64; j++) {
    int t = t0 + seg * 64 + j;
    float z = zf[(long)t * 64 + h] + bias;
    float v = (z > 20.f) ? z : log1pf(expf(z));
    dt_f[(long)t * 64 + h] = v;
    s += v * Ah;
  }
  segsum[seg][h] = s;
  __syncthreads();
  float run = 0.f;
  for (int k = 0; k < seg; k++) run += segsum[k][h];
  for (int j = 0; j < 64; j++) {
    int t = t0 + seg * 64 + j;
    run += dt_f[(long)t * 64 + h] * Ah;
    cum_f[(long)t * 64 + h] = run;
  }
  if (seg == 3) cuml[bc * 64 + h] = run;
}

// --------------------------------- states via MFMA: states[bc,h,p,n] (64x128)
// states[p][n] = sum_t (w_t * x[t][p]) * B[t][n];  w folded into A-operand.
__global__ __launch_bounds__(256) void states_mfma(const unsigned short* __restrict__ xT16,
                                                   const unsigned short* __restrict__ B16,
                                                   const float* __restrict__ dt_f,
                                                   const float* __restrict__ cum_f,
                                                   const float* __restrict__ cuml,
                                                   float* __restrict__ states) {
  int h = blockIdx.x, bc = blockIdx.y;
  int t0 = bc * 256, tid = threadIdx.x;
  __shared__ float w_s[256];
  __shared__ unsigned short Aw[64 * 40];   // [p][tt] pad 40
  __shared__ unsigned short BT[128 * 40];  // [n][tt] pad 40
  {
    int t = t0 + tid;
    w_s[tid] = expf(cuml[bc * 64 + h] - cum_f[(long)t * 64 + h]) * dt_f[(long)t * 64 + h];
  }
  __syncthreads();
  int wv = tid >> 6, lane = tid & 63;
  int mr = lane & 15, koff = (lane >> 4) * 8;
  f32x4 acc[4][2];
#pragma unroll
  for (int mi = 0; mi < 4; mi++)
#pragma unroll
    for (int nj = 0; nj < 2; nj++) acc[mi][nj] = f32x4{0.f, 0.f, 0.f, 0.f};
  for (int kt = 0; kt < 8; kt++) {
    {  // form Aw: thread = p*4 + tq, 8 t-elems each
      int p = tid >> 2, tq = tid & 3;
      const unsigned short* g = &xT16[((long)(h * 64 + p)) * 4096 + t0 + kt * 32 + tq * 8];
      ushort4 u0 = *(const ushort4*)g, u1 = *(const ushort4*)(g + 4);
      const float* wp = &w_s[kt * 32 + tq * 8];
      ushort4 o0, o1;
      o0.x = f2h(h2f(u0.x) * wp[0]); o0.y = f2h(h2f(u0.y) * wp[1]);
      o0.z = f2h(h2f(u0.z) * wp[2]); o0.w = f2h(h2f(u0.w) * wp[3]);
      o1.x = f2h(h2f(u1.x) * wp[4]); o1.y = f2h(h2f(u1.y) * wp[5]);
      o1.z = f2h(h2f(u1.z) * wp[6]); o1.w = f2h(h2f(u1.w) * wp[7]);
      *(ushort4*)&Aw[p * 40 + tq * 8] = o0;
      *(ushort4*)&Aw[p * 40 + tq * 8 + 4] = o1;
    }
    {  // form BT: thread = tl*8 + ng; copy B16[t][n] -> BT[n][tl]
      int tl = tid >> 3, ng = tid & 7;
      const unsigned short* g = &B16[((long)(t0 + kt * 32 + tl)) * 128 + ng * 16];
#pragma unroll
      for (int j = 0; j < 16; j++) BT[(ng * 16 + j) * 40 + tl] = g[j];
    }
    __syncthreads();
    f16x8 af[4], bf[2];
#pragma unroll
    for (int mi = 0; mi < 4; mi++)
      af[mi] = *(const f16x8*)&Aw[(mi * 16 + mr) * 40 + koff];
#pragma unroll
    for (int nj = 0; nj < 2; nj++)
      bf[nj] = *(const f16x8*)&BT[((wv * 2 + nj) * 16 + mr) * 40 + koff];
#pragma unroll
    for (int mi = 0; mi < 4; mi++)
#pragma unroll
      for (int nj = 0; nj < 2; nj++)
        acc[mi][nj] = __builtin_amdgcn_mfma_f32_16x16x32_f16(af[mi], bf[nj],
                                                             acc[mi][nj], 0, 0, 0);
    __syncthreads();
  }
  int cl = lane & 15, rq = (lane >> 4) * 4;
  long base = ((long)(bc * 64 + h)) * 8192;
#pragma unroll
  for (int mi = 0; mi < 4; mi++)
#pragma unroll
    for (int r = 0; r < 4; r++) {
      int p = mi * 16 + rq + r;
#pragma unroll
      for (int nj = 0; nj < 2; nj++) {
        int n = (wv * 2 + nj) * 16 + cl;
        states[base + p * 128 + n] = acc[mi][nj][r];
      }
    }
}

// --------------------------------- inter-chunk recurrence (in-place -> prevs)
__global__ __launch_bounds__(256) void recur_kernel(float* __restrict__ states,
                                                    const float* __restrict__ cuml) {
  int bh = blockIdx.x;
  int b = bh >> 6, h = bh & 63;
  int tid = threadIdx.x;
  float4 prev[8];
#pragma unroll
  for (int j = 0; j < 8; j++) prev[j] = make_float4(0.f, 0.f, 0.f, 0.f);
  for (int c = 0; c < 8; c++) {
    int bc = b * 8 + c;
    float cd = expf(cuml[bc * 64 + h]);
    long base = (long)(bc * 64 + h) * 8192;
#pragma unroll
    for (int j = 0; j < 8; j++) {
      long o = base + j * 1024 + tid * 4;
      float4 st = *reinterpret_cast<const float4*>(&states[o]);
      *reinterpret_cast<float4*>(&states[o]) = prev[j];
      prev[j].x = fmaf(cd, prev[j].x, st.x);
      prev[j].y = fmaf(cd, prev[j].y, st.y);
      prev[j].z = fmaf(cd, prev[j].z, st.z);
      prev[j].w = fmaf(cd, prev[j].w, st.w);
    }
  }
}

// ---------------- fused Y = Ydiag + Yoff + D*x  via MFMA, per (h, bc) block
// Ydiag[i][p] = sum_j S[i][j]*x[j][p],  S = CBT*exp(cum_i-cum_j)*dt_j, causal.
// Yoff[i][p]  = sum_n (C[i][n]*fac_i)*PS[p][n],  fac_i = exp(cum_i).
__global__ __launch_bounds__(256) void yfused(const unsigned short* __restrict__ xT16,
                                              const unsigned short* __restrict__ x16,
                                              const unsigned short* __restrict__ C16,
                                              const float* __restrict__ CBT,
                                              const float* __restrict__ states,
                                              const float* __restrict__ dt_f,
                                              const float* __restrict__ cum_f,
                                              const float* __restrict__ Dp,
                                              float* __restrict__ Ysum) {
  int h = blockIdx.x, bc = blockIdx.y;
  int t0 = bc * 256, tid = threadIdx.x;
  __shared__ unsigned short Sb[256 * 40];   // S / Afac tile [256][32] pad 40
  __shared__ unsigned short Xb[64 * 264];   // xT [64][256] pad 264; later PS16 [64][136]
  __shared__ float cum_s[256], dt_s[256];
  int i = tid;
  cum_s[i] = cum_f[(long)(t0 + i) * 64 + h];
  dt_s[i] = dt_f[(long)(t0 + i) * 64 + h];
  {  // stage xT tile: thread = p*4 + tq, 64 t-elems each
    int p = tid >> 2, tq = tid & 3;
    const unsigned short* g = &xT16[((long)(h * 64 + p)) * 4096 + t0 + tq * 64];
    unsigned short* l = &Xb[p * 264 + tq * 64];
#pragma unroll
    for (int c = 0; c < 8; c++)
      *(uint4*)(l + c * 8) = *(const uint4*)(g + c * 8);
  }
  __syncthreads();
  float cum_i = cum_s[i];
  const float* cbrow = CBT + (long)bc * 65536 + (long)i * 256;
  int wv = tid >> 6, lane = tid & 63;
  int mr = lane & 15, koff = (lane >> 4) * 8;
  f32x4 acc[4][4];
#pragma unroll
  for (int mi = 0; mi < 4; mi++)
#pragma unroll
    for (int ni = 0; ni < 4; ni++) acc[mi][ni] = f32x4{0.f, 0.f, 0.f, 0.f};
  // ---------------- ydiag phase: K = 256 over j, 8 k-tiles
  for (int kt = 0; kt < 8; kt++) {
    int k0 = kt * 32;
#pragma unroll
    for (int c = 0; c < 8; c++) {
      float4 cb = *(const float4*)&cbrow[k0 + c * 4];
      ushort4 o;
      {
        int j = k0 + c * 4 + 0;
        float s = (j <= i) ? cb.x * expf(cum_i - cum_s[j]) * dt_s[j] : 0.f;
        o.x = f2h(s);
      }
      {
        int j = k0 + c * 4 + 1;
        float s = (j <= i) ? cb.y * expf(cum_i - cum_s[j]) * dt_s[j] : 0.f;
        o.y = f2h(s);
      }
      {
        int j = k0 + c * 4 + 2;
        float s = (j <= i) ? cb.z * expf(cum_i - cum_s[j]) * dt_s[j] : 0.f;
        o.z = f2h(s);
      }
      {
        int j = k0 + c * 4 + 3;
        float s = (j <= i) ? cb.w * expf(cum_i - cum_s[j]) * dt_s[j] : 0.f;
        o.w = f2h(s);
      }
      *(ushort4*)&Sb[i * 40 + c * 4] = o;
    }
    __syncthreads();
    if (kt <= 2 * wv + 1) {
      f16x8 af[4], bf[4];
#pragma unroll
      for (int mi = 0; mi < 4; mi++)
        af[mi] = *(const f16x8*)&Sb[(64 * wv + mi * 16 + mr) * 40 + koff];
#pragma unroll
      for (int ni = 0; ni < 4; ni++)
        bf[ni] = *(const f16x8*)&Xb[(ni * 16 + mr) * 264 + k0 + koff];
#pragma unroll
      for (int mi = 0; mi < 4; mi++)
#pragma unroll
        for (int ni = 0; ni < 4; ni++)
          acc[mi][ni] = __builtin_amdgcn_mfma_f32_16x16x32_f16(af[mi], bf[ni],
                                                               acc[mi][ni], 0, 0, 0);
    }
    __syncthreads();
  }
  // ---------------- yoff phase: stage PS16 into Xb (xT dead)
  {
    int p = tid >> 2, nq = tid & 3;
    const float* g = &states[((long)(bc * 64 + h)) * 8192 + p * 128 + nq * 32];
    unsigned short* l = &Xb[p * 136 + nq * 32];
#pragma unroll
    for (int c = 0; c < 8; c++) {
      float4 v = *(const float4*)(g + c * 4);
      ushort4 u;
      u.x = f2h(v.x); u.y = f2h(v.y); u.z = f2h(v.z); u.w = f2h(v.w);
      *(ushort4*)(l + c * 4) = u;
    }
  }
  float fac_i = expf(cum_i);
  for (int kn = 0; kn < 4; kn++) {
    {  // form Afac row i
      const unsigned short* g = &C16[((long)(t0 + i)) * 128 + kn * 32];
#pragma unroll
      for (int c = 0; c < 8; c++) {
        ushort4 u = *(const ushort4*)(g + c * 4);
        ushort4 o;
        o.x = f2h(h2f(u.x) * fac_i); o.y = f2h(h2f(u.y) * fac_i);
        o.z = f2h(h2f(u.z) * fac_i); o.w = f2h(h2f(u.w) * fac_i);
        *(ushort4*)&Sb[i * 40 + c * 4] = o;
      }
    }
    __syncthreads();
    f16x8 af[4], bf[4];
#pragma unroll
    for (int mi = 0; mi < 4; mi++)
      af[mi] = *(const f16x8*)&Sb[(64 * wv + mi * 16 + mr) * 40 + koff];
#pragma unroll
    for (int ni = 0; ni < 4; ni++)
      bf[ni] = *(const f16x8*)&Xb[(ni * 16 + mr) * 136 + kn * 32 + koff];
#pragma unroll
    for (int mi = 0; mi < 4; mi++)
#pragma unroll
      for (int ni = 0; ni < 4; ni++)
        acc[mi][ni] = __builtin_amdgcn_mfma_f32_16x16x32_f16(af[mi], bf[ni],
                                                             acc[mi][ni], 0, 0, 0);
    __syncthreads();
  }
  // epilogue: + D*x, store Ysum fp32
  float Dh = Dp[h];
  int cl = lane & 15, rq = (lane >> 4) * 4;
#pragma unroll
  for (int mi = 0; mi < 4; mi++)
#pragma unroll
    for (int r = 0; r < 4; r++) {
      long row = t0 + 64 * wv + mi * 16 + rq + r;
      float* yr = &Ysum[row * 4096 + h * 64];
      const unsigned short* xr = &x16[row * 4096 + h * 64];
#pragma unroll
      for (int ni = 0; ni < 4; ni++) {
        int p = ni * 16 + cl;
        yr[p] = acc[mi][ni][r] + Dh * h2f(xr[p]);
      }
    }
}

// ------------------------------------------------- gate*SiLU + RMSNorm -> fp16
__global__ __launch_bounds__(256) void norm_kernel(const float* __restrict__ Ysum,
                                                   const _Float16* __restrict__ gate,
                                                   const float* __restrict__ nw,
                                                   _Float16* __restrict__ hid) {
  int t = blockIdx.x;
  int tid = threadIdx.x;
  float hv[16];
  float ss = 0.f;
#pragma unroll
  for (int k = 0; k < 4; k++) {
    int d = tid * 4 + k * 1024;
    float4 y = *reinterpret_cast<const float4*>(&Ysum[(long)t * 4096 + d]);
    ushort4 gu = *reinterpret_cast<const ushort4*>(gate + (long)t * 4096 + d);
    float h0 = y.x * siluf(h2f(gu.x)), h1 = y.y * siluf(h2f(gu.y));
    float h2 = y.z * siluf(h2f(gu.z)), h3 = y.w * siluf(h2f(gu.w));
    hv[k * 4 + 0] = h0; hv[k * 4 + 1] = h1; hv[k * 4 + 2] = h2; hv[k * 4 + 3] = h3;
    ss += h0 * h0 + h1 * h1 + h2 * h2 + h3 * h3;
  }
#pragma unroll
  for (int o = 32; o > 0; o >>= 1) ss += __shfl_down(ss, o, 64);
  __shared__ float ws4[4];
  if ((tid & 63) == 0) ws4[tid >> 6] = ss;
  __syncthreads();
  float var = (ws4[0] + ws4[1] + ws4[2] + ws4[3]) * (1.f / 4096.f);
  float scale = rsqrtf(var + 1e-5f);
#pragma unroll
  for (int k = 0; k < 4; k++) {
    int d = tid * 4 + k * 1024;
    ushort4 u;
#pragma unroll
    for (int c = 0; c < 4; c++)
      ((unsigned short*)&u)[c] = f2h(hv[k * 4 + c] * scale * nw[d + c]);
    *reinterpret_cast<ushort4*>(hid + (long)t * 4096 + d) = u;
  }
}

// =============================================================== launch
extern "C" void kernel_launch(void* const* d_in, const int* in_sizes, int n_in,
                              void* d_out, int out_size, void* d_ws, size_t ws_size,
                              hipStream_t stream) {
  (void)in_sizes; (void)n_in; (void)out_size; (void)ws_size;
  const float* hs    = (const float*)d_in[0];
  const float* Win   = (const float*)d_in[1];
  const float* convw = (const float*)d_in[2];
  const float* convb = (const float*)d_in[3];
  const float* dtb   = (const float*)d_in[4];
  const float* Alog  = (const float*)d_in[5];
  const float* Dp    = (const float*)d_in[6];
  const float* nw    = (const float*)d_in[7];
  const float* Wout  = (const float*)d_in[8];
  float* out = (float*)d_out;

  char* base = (char*)d_ws;
  size_t off = 0;
  auto take = [&](size_t n) { char* r = base + off; off += (n + 255) & ~(size_t)255; return r; };
  float*    hbcf  = (float*)take(4096UL * 4352 * 4);    // gemm_in -> conv; then Ysum
  _Float16* gateh = (_Float16*)take(4096UL * 4096 * 2); // gemm_in -> norm
  _Float16* Ah    = (_Float16*)take(4096UL * 2048 * 2); // cast -> gemm_in; then WoutT
  _Float16* WtH   = (_Float16*)take(8448UL * 2048 * 2); // trans -> gemm_in; then x16
  _Float16* xT16  = (_Float16*)take(4096UL * 4096 * 2); // xtrans -> states/yfused
  _Float16* B16   = (_Float16*)take(4096UL * 128 * 2);
  _Float16* C16   = (_Float16*)take(4096UL * 128 * 2);
  float*    zf    = (float*)take(4096UL * 64 * 4);
  float*    dt_f  = (float*)take(4096UL * 64 * 4);
  float*    cum_f = (float*)take(4096UL * 64 * 4);
  float*    cuml  = (float*)take(16UL * 64 * 4);
  float*    CBT   = (float*)take(16UL * 256 * 256 * 4);
  float*    states= (float*)take(1024UL * 8192 * 4);    // -> prevs in-place; then hid
  // overlays:
  float*    Ysum  = hbcf;               // live yfused..norm
  _Float16* WoutT = Ah;                 // written after gemm_in
  _Float16* x16   = WtH;                // 33.6MB in 34.6MB, written by conv
  _Float16* hid   = (_Float16*)states;  // live norm..out_proj

  dim3 tb(32, 8);
  // 1. casts / transposes / exact dt slice
  cast_f16<<<8192, 256, 0, stream>>>(hs, Ah);
  transpose_win<<<dim3(264, 64), tb, 0, stream>>>(Win, WtH);
  dtz_kernel<<<1024, 256, 0, stream>>>(hs, Win, zf);
  // 2. fp16 in_proj GEMM -> gate (fp16) + hbc (fp32)
  gemm_in<<<dim3(66, 32), 256, 0, stream>>>(Ah, WtH, gateh, hbcf);
  // 3. out_proj weight transpose into dead Ah
  transpose_wout<<<dim3(64, 128), tb, 0, stream>>>(Wout, WoutT, 4096, 2048);
  // 4. conv + silu -> x16, B16, C16 (fp16)
  conv_silu_kernel<<<dim3(17, 4096), 256, 0, stream>>>(hbcf, convw, convb, x16, B16, C16);
  // 5. dt softplus + cumsum (fp32-exact)
  dt_cum_kernel<<<16, 256, 0, stream>>>(zf, dtb, Alog, dt_f, cum_f, cuml);
  // 6. x16 -> xT16 global transpose
  xtrans<<<dim3(64, 64), 256, 0, stream>>>((const unsigned short*)x16, (unsigned short*)xT16);
  // 7. CBT = C.B^T per chunk (fp16 MFMA, fp32 out)
  gemm_bt<<<dim3(2, 2, 16), 256, 0, stream>>>(C16, B16, CBT, 128, 256,
                                              32768, 32768, 65536);
  // 8. per-chunk states (fp16 MFMA, fp32 out)
  states_mfma<<<dim3(64, 16), 256, 0, stream>>>((const unsigned short*)xT16,
                                                (const unsigned short*)B16,
                                                dt_f, cum_f, cuml, states);
  // 9. inter-chunk recurrence (in-place, fp32)
  recur_kernel<<<128, 256, 0, stream>>>(states, cuml);
  // 10. fused Ydiag + Yoff + D*x -> Ysum (overlays dead hbcf)
  yfused<<<dim3(64, 16), 256, 0, stream>>>((const unsigned short*)xT16,
                                           (const unsigned short*)x16,
                                           (const unsigned short*)C16,
                                           CBT, states, dt_f, cum_f, Dp, Ysum);
  // 11. gate + RMSNorm -> hid fp16 (overlays dead states)
  norm_kernel<<<4096, 256, 0, stream>>>(Ysum, gateh, nw, hid);
  // 12. out_proj GEMM (fp16) -> d_out fp32
  gemm_bt<<<dim3(16, 32, 1), 256, 0, stream>>>(hid, WoutT, out, 4096, 2048, 0, 0, 0);
}